// Round 14
// baseline (287.491 us; speedup 1.0000x reference)
//
#include <hip/hip_runtime.h>
#include <math.h>

#define BATCH 8
#define SEQ   2048
#define DIM   512
#define NCH   16
#define CHW   128
#define CAP   512

typedef unsigned int u32;
typedef unsigned long long u64;
typedef _Float16 h2  __attribute__((ext_vector_type(2)));
typedef _Float16 h8  __attribute__((ext_vector_type(8)));
typedef float    f4  __attribute__((ext_vector_type(4)));
typedef u32      u4v __attribute__((ext_vector_type(4)));

#define MFMA16(a,b,c) __builtin_amdgcn_mfma_f32_16x16x32_f16((a),(b),(c),0,0,0)

struct HL { u32 hi, lo; };
__device__ __forceinline__ HL split2t(float a, float b) {
    _Float16 ha = (_Float16)a, hb = (_Float16)b;
    h2 th; th[0] = ha; th[1] = hb;
    h2 tl; tl[0] = (_Float16)(a - (float)ha); tl[1] = (_Float16)(b - (float)hb);
    HL r; r.hi = __builtin_bit_cast(u32, th); r.lo = __builtin_bit_cast(u32, tl);
    return r;
}
__device__ __forceinline__ u32 fkey(float f) {
    u32 v = __builtin_bit_cast(u32, f);
    return (v & 0x80000000u) ? ~v : (v | 0x80000000u);
}

// ============ prep_q: Q -> hi/lo f16 pairs, layout [b][row][d-pair] ============
__global__ __launch_bounds__(256, 4)
void prep_q_kernel(const float* __restrict__ Q, u32* __restrict__ Qh, u32* __restrict__ Ql)
{
    const int gidx = blockIdx.x * 256 + threadIdx.x;   // (b, row, 8-d chunk c)
    const int c   = gidx & 63;
    const int row = (gidx >> 6) & 2047;
    const int b   = gidx >> 17;
    const float* src = Q + ((size_t)(b * SEQ + row)) * DIM + 8 * c;
    const f4 r0 = *(const f4*)(src);
    const f4 r1 = *(const f4*)(src + 4);
    const HL p0 = split2t(r0[0], r0[1]);
    const HL p1 = split2t(r0[2], r0[3]);
    const HL p2 = split2t(r1[0], r1[1]);
    const HL p3 = split2t(r1[2], r1[3]);
    u4v vh = {p0.hi, p1.hi, p2.hi, p3.hi};
    u4v vl = {p0.lo, p1.lo, p2.lo, p3.lo};
    const size_t off = ((size_t)(b * SEQ + row)) * 256 + 4 * c;
    *(u4v*)(Qh + off) = vh;
    *(u4v*)(Ql + off) = vl;
}

// ==== prep_k: K -> hi/lo f16 pairs, fragment-native K^T layout [b][g][s][4] ====
__global__ __launch_bounds__(256, 4)
void prep_k_kernel(const float* __restrict__ K, u32* __restrict__ Kh, u32* __restrict__ Kl)
{
    const int b = blockIdx.x >> 6;       // 8 batches
    const int g = blockIdx.x & 63;       // d-pair group (8 d per group)
    #pragma unroll
    for (int i = 0; i < 8; i++) {
        const int s = 256 * i + threadIdx.x;
        const float* src = K + ((size_t)(b * SEQ + s)) * DIM + 8 * g;
        const f4 r0 = *(const f4*)(src);
        const f4 r1 = *(const f4*)(src + 4);
        const HL p0 = split2t(r0[0], r0[1]);
        const HL p1 = split2t(r0[2], r0[3]);
        const HL p2 = split2t(r1[0], r1[1]);
        const HL p3 = split2t(r1[2], r1[3]);
        u4v vh = {p0.hi, p1.hi, p2.hi, p3.hi};
        u4v vl = {p0.lo, p1.lo, p2.lo, p3.lo};
        const size_t off = ((size_t)(b * 64 + g) * SEQ + s) * 4;
        *(u4v*)(Kh + off) = vh;   // coalesced: consecutive s -> consecutive 16B
        *(u4v*)(Kl + off) = vl;
    }
}

// ======= argmin2: one wave = one (16-row group, s-tile) job; LDS/barrier-free =======
// Maps (R5-R12 validated): A row=lane&15, slot e<->k=8lg+e; B col=lane&15 same;
// C/D row=4lg+reg, col=lane&15.
__global__ __launch_bounds__(256, 2)
void argmin2_kernel(const u32* __restrict__ Qh, const u32* __restrict__ Ql,
                    const u32* __restrict__ Kh, const u32* __restrict__ Kl,
                    const int* __restrict__ mfp, u64* __restrict__ keys)
{
    if (mfp[0] == 0) return;

    const int tid  = threadIdx.x;
    const int wj   = blockIdx.x * 4 + (tid >> 6);   // 8704 wave-jobs exactly
    const int lane = tid & 63, lx = lane & 15, lg = lane >> 4;

    // decode: per batch 1088 jobs; band a (groups 8a..8a+7) has 8*(16-a) jobs
    const int b = wj / 1088;
    int rem = wj - b * 1088;
    int a = 0;
    while (rem >= 8 * (16 - a)) { rem -= 8 * (16 - a); a++; }
    const int gl = rem / (16 - a);
    const int jj = rem - gl * (16 - a);
    const int g16 = 8 * a + gl;          // 16-row group 0..127
    const int m0  = 16 * g16;
    const int s0  = 128 * (a + jj);

    // ---- A fragments: 32 aligned b128 loads from pre-split Q ----
    u4v qh_[16], ql_[16];
    {
        const size_t rb = ((size_t)(b * SEQ + m0 + lx)) * 256;
        #pragma unroll
        for (int t = 0; t < 16; t++) {
            qh_[t] = *(const u4v*)(Qh + rb + 16 * t + 4 * lg);
            ql_[t] = *(const u4v*)(Ql + rb + 16 * t + 4 * lg);
        }
    }

    const f4 fz = {0.f, 0.f, 0.f, 0.f};
    f4 sa[8];
    #pragma unroll
    for (int nt = 0; nt < 8; nt++) sa[nt] = fz;

    // ---- main loop: 256 b128 loads + 384 MFMA, no LDS, no barriers ----
    const size_t kb = ((size_t)(b * 64) * SEQ + s0 + lx) * 4;
    #pragma unroll 4
    for (int t = 0; t < 16; t++) {
        const size_t rowoff = kb + (size_t)(4 * t + lg) * (SEQ * 4);
        #pragma unroll
        for (int nt = 0; nt < 8; nt++) {
            const u4v kh = *(const u4v*)(Kh + rowoff + 64 * nt);
            const u4v kl = *(const u4v*)(Kl + rowoff + 64 * nt);
            const h8 ah = __builtin_bit_cast(h8, qh_[t]);
            const h8 al = __builtin_bit_cast(h8, ql_[t]);
            sa[nt] = MFMA16(ah, __builtin_bit_cast(h8, kh), sa[nt]);
            sa[nt] = MFMA16(ah, __builtin_bit_cast(h8, kl), sa[nt]);
            sa[nt] = MFMA16(al, __builtin_bit_cast(h8, kh), sa[nt]);
        }
    }

    // ---- NaN scrub (insurance) + masked argmin + atomicMin ----
    #pragma unroll
    for (int nt = 0; nt < 8; nt++)
        #pragma unroll
        for (int r = 0; r < 4; r++) {
            float s = sa[nt][r];
            sa[nt][r] = (s == s) ? s : 0.0f;
        }
    #pragma unroll
    for (int r = 0; r < 4; r++) {
        const int tg = m0 + 4 * lg + r;
        float mv = INFINITY; int mi = -1;
        #pragma unroll
        for (int nt = 0; nt < 8; nt++) {
            const int sg = s0 + 16 * nt + lx;
            const float v = sa[nt][r];
            if (sg >= tg && v < mv) { mv = v; mi = sg; }
        }
        #pragma unroll
        for (int off = 1; off < 16; off <<= 1) {
            const float ov = __shfl_xor(mv, off);
            const int   oi = __shfl_xor(mi, off);
            if (ov < mv || (ov == mv && oi >= 0 && (mi < 0 || oi < mi))) { mv = ov; mi = oi; }
        }
        if (lx == 0 && mi >= 0) {
            const u64 pk = ((u64)fkey(mv) << 32) | (u32)mi;
            atomicMin(&keys[(size_t)b * SEQ + tg], pk);
        }
    }
}

// ================= argmin_lds: R11-verbatim fallback (small ws) =================
__global__ __launch_bounds__(512, 2)
void argmin_lds_kernel(const float* __restrict__ Q, const float* __restrict__ K,
                       const int* __restrict__ mfp, u64* __restrict__ ws)
{
    if (mfp[0] == 0) return;
    __shared__ u32 KTh[2][128][32];
    __shared__ u32 KTl[2][128][32];
    __shared__ float sx[128][68];

    const int tid  = threadIdx.x;
    const int w    = tid >> 6, wp = w & 3, h = w >> 2;
    const int lane = tid & 63, lx = lane & 15, lg = lane >> 4;

    int j = blockIdx.x;
    const int b = j / 272; j -= b * 272;
    int mg = 0;
    while (true) { const int n = 16 - (mg >> 1); if (j < n) break; j -= n; mg++; }
    const int m0 = mg * 64;
    const int s0 = (m0 & ~127) + 128 * j;

    const float* __restrict__ Qb = Q + (size_t)b * SEQ * DIM;
    const float* __restrict__ Kb = K + (size_t)b * SEQ * DIM;
    const int krow = (tid >> 1) & 127;
    const int ksc  = tid & 1;

    h8 qh[8], ql[8];
    {
        const float* qrowp = Qb + (size_t)(m0 + 16 * wp + lx) * DIM;
        #pragma unroll
        for (int t = 0; t < 8; t++) {
            float bufv[8];
            *(f4*)&bufv[0] = *(const f4*)(qrowp + 256 * h + 32 * t + 8 * lg);
            *(f4*)&bufv[4] = *(const f4*)(qrowp + 256 * h + 32 * t + 8 * lg + 4);
            u4v uh, ul;
            #pragma unroll
            for (int p = 0; p < 4; p++) {
                const HL hl = split2t(bufv[2*p], bufv[2*p+1]);
                uh[p] = hl.hi; ul[p] = hl.lo;
            }
            qh[t] = __builtin_bit_cast(h8, uh);
            ql[t] = __builtin_bit_cast(h8, ul);
        }
    }
    const f4 fz = {0.f, 0.f, 0.f, 0.f};
    f4 sa[8];
    #pragma unroll
    for (int nt = 0; nt < 8; nt++) sa[nt] = fz;

    f4 kreg[8];
    #pragma unroll
    for (int c = 0; c < 8; c++)
        kreg[c] = *(const f4*)(Kb + (size_t)(s0 + krow) * DIM + 256 * h + 32 * ksc + 4 * c);

    #pragma unroll
    for (int i = 0; i < 4; i++) {
        if (i) __syncthreads();
        {
            u32 HH[16], LL[16];
            #pragma unroll
            for (int c = 0; c < 8; c++) {
                const HL e0 = split2t(kreg[c][0], kreg[c][1]);
                const HL e1 = split2t(kreg[c][2], kreg[c][3]);
                HH[2*c] = e0.hi;   LL[2*c] = e0.lo;
                HH[2*c+1] = e1.hi; LL[2*c+1] = e1.lo;
            }
            #pragma unroll
            for (int qd = 0; qd < 4; qd++) {
                const int gp = ((4 * ksc + qd) ^ (krow & 7)) * 4;
                u4v vh = {HH[4*qd], HH[4*qd+1], HH[4*qd+2], HH[4*qd+3]};
                u4v vl = {LL[4*qd], LL[4*qd+1], LL[4*qd+2], LL[4*qd+3]};
                *(u4v*)&KTh[h][krow][gp] = vh;
                *(u4v*)&KTl[h][krow][gp] = vl;
            }
        }
        __syncthreads();
        if (i < 3) {
            #pragma unroll
            for (int c = 0; c < 8; c++)
                kreg[c] = *(const f4*)(Kb + (size_t)(s0 + krow) * DIM
                                       + 256 * h + 64 * (i + 1) + 32 * ksc + 4 * c);
        }
        __builtin_amdgcn_s_setprio(1);
        #pragma unroll
        for (int tl = 0; tl < 2; tl++) {
            const int t = 2 * i + tl;
            #pragma unroll
            for (int nt = 0; nt < 8; nt++) {
                const int s  = 16 * nt + lx;
                const int gp = ((4 * tl + lg) ^ (s & 7)) * 4;
                const h8 kh = __builtin_bit_cast(h8, *(const u4v*)&KTh[h][s][gp]);
                const h8 kl = __builtin_bit_cast(h8, *(const u4v*)&KTl[h][s][gp]);
                sa[nt] = MFMA16(qh[t], kh, sa[nt]);
                sa[nt] = MFMA16(qh[t], kl, sa[nt]);
                sa[nt] = MFMA16(ql[t], kh, sa[nt]);
            }
        }
        __builtin_amdgcn_s_setprio(0);
    }

    if (h == 0) {
        #pragma unroll
        for (int nt = 0; nt < 8; nt++)
            *(f4*)&sx[16 * nt + lx][16 * wp + 4 * lg] = sa[nt];
    }
    __syncthreads();
    if (h == 1) {
        #pragma unroll
        for (int nt = 0; nt < 8; nt++) {
            const f4 part = *(const f4*)&sx[16 * nt + lx][16 * wp + 4 * lg];
            #pragma unroll
            for (int r = 0; r < 4; r++) {
                float s = sa[nt][r] + part[r];
                sa[nt][r] = (s == s) ? s : 0.0f;
            }
        }
        #pragma unroll
        for (int r = 0; r < 4; r++) {
            const int tg = m0 + 16 * wp + 4 * lg + r;
            float mv = INFINITY; int mi = -1;
            #pragma unroll
            for (int nt = 0; nt < 8; nt++) {
                const int sg = s0 + 16 * nt + lx;
                const float v = sa[nt][r];
                if (sg >= tg && v < mv) { mv = v; mi = sg; }
            }
            #pragma unroll
            for (int off = 1; off < 16; off <<= 1) {
                const float ov = __shfl_xor(mv, off);
                const int   oi = __shfl_xor(mi, off);
                if (ov < mv || (ov == mv && oi >= 0 && (mi < 0 || oi < mi))) { mv = ov; mi = oi; }
            }
            if (lx == 0 && mi >= 0) {
                const u64 pk = ((u64)fkey(mv) << 32) | (u32)mi;
                atomicMin(&ws[(size_t)b * SEQ + tg], pk);
            }
        }
    }
}

// ================= gather + worklist (R10-verbatim) =================
__global__ __launch_bounds__(512, 2)
void gather_kernel(const float* __restrict__ V, const u64* __restrict__ keys,
                   u32* __restrict__ cnt, u32* __restrict__ list,
                   float* __restrict__ Out)
{
    const int tid  = threadIdx.x;
    const int w    = tid >> 6;
    const int lane = tid & 63;
    const int b    = blockIdx.x >> 5;
    const int m0   = (blockIdx.x & 31) * 64;

    const float* __restrict__ Vb = V + (size_t)b * SEQ * DIM;
    float* __restrict__ Ob = Out + (size_t)b * SEQ * DIM;

    #pragma unroll
    for (int rr = 0; rr < 8; rr++) {
        const int tg = m0 + 8 * w + rr;
        const u64 pk = keys[(size_t)b * SEQ + tg];
        const u32 key = (u32)(pk >> 32);
        if (key < 0x80000000u) {
            const int ss = (int)(pk & 0xFFFFFFFFu);
            #pragma unroll
            for (int it = 0; it < 2; it++) {
                const int col = 256 * it + 4 * lane;
                *(f4*)(Ob + (size_t)tg * DIM + col) = *(const f4*)(Vb + (size_t)ss * DIM + col);
            }
        } else if (lane == 0) {
            const u32 p = atomicAdd(cnt, 1u);
            list[p] = ((u32)b << 16) | (u32)tg;
        }
    }
}

// ====== fb_part (R11-verbatim) ======
__global__ __launch_bounds__(512, 2)
void fb_part_kernel(const float* __restrict__ Q, const float* __restrict__ K,
                    const float* __restrict__ V, const int* __restrict__ mfp,
                    const u32* __restrict__ cnt, const u32* __restrict__ list,
                    float2* __restrict__ meta, float* __restrict__ partials)
{
    __shared__ float qrow[DIM];
    __shared__ float zpart[4][CHW];
    __shared__ float zs[CHW];
    __shared__ float zp[CHW];
    __shared__ f4    pacc[4][128];
    __shared__ float red2[2];

    const int tid = threadIdx.x;
    const int mf  = mfp[0];
    const float dk = 22.627416997969522f;

    const int n  = (int)cnt[0];
    const int nw = min(n * NCH, CAP);

    for (int wi = blockIdx.x; wi < nw; wi += gridDim.x) {
        const int ridx  = wi >> 4;
        const int chunk = wi & 15;
        const u32 e  = list[ridx];
        const int b  = (int)(e >> 16);
        const int tg = (int)(e & 0xFFFFu);

        const float* __restrict__ Qb = Q + (size_t)b * SEQ * DIM;
        const float* __restrict__ Kb = K + (size_t)b * SEQ * DIM;
        const float* __restrict__ Vb = V + (size_t)b * SEQ * DIM;

        if (tid < 128) *(f4*)&qrow[4 * tid] = *(const f4*)(Qb + (size_t)tg * DIM + 4 * tid);
        __syncthreads();
        {
            const int jj   = tid & 127;
            const int dseg = tid >> 7;
            const int col  = chunk * CHW + jj;
            const float* kr = Kb + (size_t)col * DIM + 128 * dseg;
            float acc = 0.f;
            #pragma unroll 8
            for (int d4 = 0; d4 < 32; d4++) {
                const f4 q = *(const f4*)&qrow[4 * (32 * dseg + d4)];
                const f4 k = *(const f4*)(kr + 4 * d4);
                acc += q[0]*k[0] + q[1]*k[1] + q[2]*k[2] + q[3]*k[3];
            }
            zpart[dseg][jj] = acc;
        }
        __syncthreads();
        if (tid < 128) {
            const int col = chunk * CHW + tid;
            float z = zpart[0][tid] + zpart[1][tid] + zpart[2][tid] + zpart[3][tid];
            const float mult = (mf && col >= tg) ? -1.0e9f : 1.0f;
            zs[tid] = z * mult / dk;
        }
        __syncthreads();
        if (tid < 64) {
            float m = fmaxf(zs[tid], zs[tid + 64]);
            #pragma unroll
            for (int off = 1; off < 64; off <<= 1) m = fmaxf(m, __shfl_xor(m, off));
            if (tid == 0) red2[0] = m;
        }
        __syncthreads();
        const float M = red2[0];
        if (tid < 128) zp[tid] = expf(zs[tid] - M);
        __syncthreads();
        if (tid < 64) {
            float s = zp[tid] + zp[tid + 64];
            #pragma unroll
            for (int off = 1; off < 64; off <<= 1) s += __shfl_xor(s, off);
            if (tid == 0) red2[1] = s;
        }
        {
            const int dq   = tid & 127;
            const int sseg = tid >> 7;
            f4 acc = {0.f, 0.f, 0.f, 0.f};
            const int sb = chunk * CHW + 32 * sseg;
            #pragma unroll 8
            for (int s = 0; s < 32; s++)
                acc += zp[32 * sseg + s] * *(const f4*)(Vb + (size_t)(sb + s) * DIM + 4 * dq);
            pacc[sseg][dq] = acc;
        }
        __syncthreads();
        if (tid < 128) {
            const f4 nc = pacc[0][tid] + pacc[1][tid] + pacc[2][tid] + pacc[3][tid];
            *(f4*)&partials[(size_t)wi * DIM + 4 * tid] = nc;
        }
        if (tid == 0) meta[wi] = make_float2(M, red2[1]);
        __syncthreads();
    }
}

// ====== fb_combine (R11-verbatim) ======
__global__ __launch_bounds__(512, 2)
void fb_combine_kernel(const float* __restrict__ Q, const float* __restrict__ K,
                       const float* __restrict__ V, const int* __restrict__ mfp,
                       const u32* __restrict__ cnt, const u32* __restrict__ list,
                       const float2* __restrict__ meta, const float* __restrict__ partials,
                       float* __restrict__ Out)
{
    __shared__ float qrow[DIM];
    __shared__ float zrow[SEQ];
    __shared__ float red[8];
    __shared__ f4    pacc[4][128];

    const int tid  = threadIdx.x;
    const int w    = tid >> 6;
    const int lane = tid & 63;
    const int mf   = mfp[0];
    const float dk = 22.627416997969522f;

    const int n = (int)cnt[0];
    for (int idx = blockIdx.x; idx < n; idx += gridDim.x) {
        const u32 e  = list[idx];
        const int b  = (int)(e >> 16);
        const int tg = (int)(e & 0xFFFFu);
        float* __restrict__ Ob = Out + (size_t)b * SEQ * DIM;

        if (idx < CAP / NCH) {
            float M = -INFINITY;
            #pragma unroll
            for (int c = 0; c < NCH; c++) M = fmaxf(M, meta[idx * NCH + c].x);
            float L = 0.f, o = 0.f;
            #pragma unroll
            for (int c = 0; c < NCH; c++) {
                const float2 mc = meta[idx * NCH + c];
                const float fct = expf(mc.x - M);
                L += mc.y * fct;
                o += partials[(size_t)(idx * NCH + c) * DIM + tid] * fct;
            }
            Ob[(size_t)tg * DIM + tid] = o / L;
        } else {
            const float* __restrict__ Qb = Q + (size_t)b * SEQ * DIM;
            const float* __restrict__ Kb = K + (size_t)b * SEQ * DIM;
            const float* __restrict__ Vb = V + (size_t)b * SEQ * DIM;
            if (tid < 128) *(f4*)&qrow[4 * tid] = *(const f4*)(Qb + (size_t)tg * DIM + 4 * tid);
            __syncthreads();
            float z4[4];
            #pragma unroll
            for (int c4 = 0; c4 < 4; c4++) {
                const int col = tid + 512 * c4;
                const float* kr = Kb + (size_t)col * DIM;
                float acc = 0.f;
                #pragma unroll 4
                for (int d4 = 0; d4 < 128; d4++) {
                    const f4 q = *(const f4*)&qrow[4 * d4];
                    const f4 k = *(const f4*)(kr + 4 * d4);
                    acc += q[0]*k[0] + q[1]*k[1] + q[2]*k[2] + q[3]*k[3];
                }
                const float mult = (mf && col >= tg) ? -1.0e9f : 1.0f;
                z4[c4] = acc * mult / dk;
            }
            float lm = fmaxf(fmaxf(z4[0], z4[1]), fmaxf(z4[2], z4[3]));
            #pragma unroll
            for (int off = 1; off < 64; off <<= 1) lm = fmaxf(lm, __shfl_xor(lm, off));
            if (lane == 0) red[w] = lm;
            __syncthreads();
            float M = red[0];
            #pragma unroll
            for (int i = 1; i < 8; i++) M = fmaxf(M, red[i]);
            float ls = 0.f;
            #pragma unroll
            for (int c4 = 0; c4 < 4; c4++) {
                const float p = expf(z4[c4] - M);
                zrow[tid + 512 * c4] = p;
                ls += p;
            }
            #pragma unroll
            for (int off = 1; off < 64; off <<= 1) ls += __shfl_xor(ls, off);
            __syncthreads();
            if (lane == 0) red[w] = ls;
            __syncthreads();
            float L = 0.f;
            #pragma unroll
            for (int i = 0; i < 8; i++) L += red[i];
            const int dq = tid & 127;
            const int sq = tid >> 7;
            f4 acc = {0.f, 0.f, 0.f, 0.f};
            const int sbeg = 512 * sq;
            #pragma unroll 8
            for (int s = 0; s < 512; s++)
                acc += zrow[sbeg + s] * *(const f4*)(Vb + (size_t)(sbeg + s) * DIM + 4 * dq);
            pacc[sq][dq] = acc;
            __syncthreads();
            if (tid < 128) {
                f4 r = pacc[0][tid] + pacc[1][tid] + pacc[2][tid] + pacc[3][tid];
                const float il = 1.0f / L;
                r[0] *= il; r[1] *= il; r[2] *= il; r[3] *= il;
                *(f4*)(Ob + (size_t)tg * DIM + 4 * tid) = r;
            }
            __syncthreads();
        }
    }
}

extern "C" void kernel_launch(void* const* d_in, const int* in_sizes, int n_in,
                              void* d_out, int out_size, void* d_ws, size_t ws_size,
                              hipStream_t stream) {
    const float* Q  = (const float*)d_in[0];
    const float* K  = (const float*)d_in[1];
    const float* V  = (const float*)d_in[2];
    const int*   mf = (const int*)d_in[3];
    float* O = (float*)d_out;

    char* wsb = (char*)d_ws;
    u64*    keys     = (u64*)wsb;                                   // 128 KB
    u32*    cnt      = (u32*)(wsb + 131072);
    u32*    list     = (u32*)(wsb + 131072 + 256);                  // 64 KB
    float2* meta     = (float2*)(wsb + 131072 + 256 + 65536);       // 4 KB
    float*  partials = (float*)(wsb + 131072 + 256 + 65536 + 8192); // 1 MB

    const size_t SPLIT_OFF = 1310720;                 // 1.25 MB, 16B-aligned
    const size_t ARR = (size_t)BATCH * SEQ * 256 * 4; // 16 MB per array
    u32* Qh = (u32*)(wsb + SPLIT_OFF);
    u32* Ql = (u32*)(wsb + SPLIT_OFF + ARR);
    u32* Kh = (u32*)(wsb + SPLIT_OFF + 2 * ARR);
    u32* Kl = (u32*)(wsb + SPLIT_OFF + 3 * ARR);
    const bool big_ws = ws_size >= SPLIT_OFF + 4 * ARR;

    hipMemsetAsync(keys, 0xFF, (size_t)BATCH * SEQ * sizeof(u64), stream);
    hipMemsetAsync(cnt, 0, sizeof(u32), stream);

    if (big_ws) {
        prep_q_kernel<<<dim3(4096), dim3(256), 0, stream>>>(Q, Qh, Ql);
        prep_k_kernel<<<dim3(512),  dim3(256), 0, stream>>>(K, Kh, Kl);
        argmin2_kernel<<<dim3(2176), dim3(256), 0, stream>>>(Qh, Ql, Kh, Kl, mf, keys);
    } else {
        argmin_lds_kernel<<<dim3(BATCH * 272), dim3(512), 0, stream>>>(Q, K, mf, keys);
    }
    gather_kernel<<<dim3(BATCH * (SEQ / 64)), dim3(512), 0, stream>>>(V, keys, cnt, list, O);
    fb_part_kernel<<<dim3(512), dim3(512), 0, stream>>>(Q, K, V, mf, cnt, list, meta, partials);
    fb_combine_kernel<<<dim3(128), dim3(512), 0, stream>>>(Q, K, V, mf, cnt, list, meta, partials, O);
}

// Round 15
// 186.784 us; speedup vs baseline: 1.5392x; 1.5392x over previous
//
#include <hip/hip_runtime.h>
#include <math.h>

#define BATCH 8
#define SEQ   2048
#define DIM   512
#define NCH   16
#define CHW   128
#define CAP   512

typedef unsigned int u32;
typedef unsigned long long u64;
typedef _Float16 h2  __attribute__((ext_vector_type(2)));
typedef _Float16 h8  __attribute__((ext_vector_type(8)));
typedef float    f4  __attribute__((ext_vector_type(4)));
typedef u32      u4v __attribute__((ext_vector_type(4)));

#define MFMA16(a,b,c) __builtin_amdgcn_mfma_f32_16x16x32_f16((a),(b),(c),0,0,0)

struct HL { u32 hi, lo; };
__device__ __forceinline__ HL split2t(float a, float b) {
    _Float16 ha = (_Float16)a, hb = (_Float16)b;
    h2 th; th[0] = ha; th[1] = hb;
    h2 tl; tl[0] = (_Float16)(a - (float)ha); tl[1] = (_Float16)(b - (float)hb);
    HL r; r.hi = __builtin_bit_cast(u32, th); r.lo = __builtin_bit_cast(u32, tl);
    return r;
}
__device__ __forceinline__ u32 fkey(float f) {
    u32 v = __builtin_bit_cast(u32, f);
    return (v & 0x80000000u) ? ~v : (v | 0x80000000u);
}

// ============ prep_q: Q -> hi/lo f16 pairs, layout [b][row][d-pair] ============
__global__ __launch_bounds__(256, 4)
void prep_q_kernel(const float* __restrict__ Q, u32* __restrict__ Qh, u32* __restrict__ Ql)
{
    const int gidx = blockIdx.x * 256 + threadIdx.x;   // (b, row, 8-d chunk c)
    const int c   = gidx & 63;
    const int row = (gidx >> 6) & 2047;
    const int b   = gidx >> 17;
    const float* src = Q + ((size_t)(b * SEQ + row)) * DIM + 8 * c;
    const f4 r0 = *(const f4*)(src);
    const f4 r1 = *(const f4*)(src + 4);
    const HL p0 = split2t(r0[0], r0[1]);
    const HL p1 = split2t(r0[2], r0[3]);
    const HL p2 = split2t(r1[0], r1[1]);
    const HL p3 = split2t(r1[2], r1[3]);
    u4v vh = {p0.hi, p1.hi, p2.hi, p3.hi};
    u4v vl = {p0.lo, p1.lo, p2.lo, p3.lo};
    const size_t off = ((size_t)(b * SEQ + row)) * 256 + 4 * c;
    *(u4v*)(Qh + off) = vh;
    *(u4v*)(Ql + off) = vl;
}

// ==== prep_k: K -> hi/lo f16 pairs, fragment-native K^T layout [b][g][s][4] ====
__global__ __launch_bounds__(256, 4)
void prep_k_kernel(const float* __restrict__ K, u32* __restrict__ Kh, u32* __restrict__ Kl)
{
    const int b = blockIdx.x >> 6;       // 8 batches
    const int g = blockIdx.x & 63;       // d-pair group (8 d per group)
    #pragma unroll
    for (int i = 0; i < 8; i++) {
        const int s = 256 * i + threadIdx.x;
        const float* src = K + ((size_t)(b * SEQ + s)) * DIM + 8 * g;
        const f4 r0 = *(const f4*)(src);
        const f4 r1 = *(const f4*)(src + 4);
        const HL p0 = split2t(r0[0], r0[1]);
        const HL p1 = split2t(r0[2], r0[3]);
        const HL p2 = split2t(r1[0], r1[1]);
        const HL p3 = split2t(r1[2], r1[3]);
        u4v vh = {p0.hi, p1.hi, p2.hi, p3.hi};
        u4v vl = {p0.lo, p1.lo, p2.lo, p3.lo};
        const size_t off = ((size_t)(b * 64 + g) * SEQ + s) * 4;
        *(u4v*)(Kh + off) = vh;   // coalesced: consecutive s -> consecutive 16B
        *(u4v*)(Kl + off) = vl;
    }
}

// ======= argmin2: one wave = one (16-row group, s-tile) job; LDS/barrier-free =======
// R15: no fragment arrays (rule-#20 scratch fix: all Q loads inline, full unroll);
// XCD-batch affinity (b = blockIdx&7 -> batch's 4MB Kh+Kl pinned to one XCD L2).
// Maps (R5-R12 validated): A row=lane&15, slot e<->k=8lg+e; B col=lane&15 same;
// C/D row=4lg+reg, col=lane&15.
__global__ __launch_bounds__(256, 2)
void argmin2_kernel(const u32* __restrict__ Qh, const u32* __restrict__ Ql,
                    const u32* __restrict__ Kh, const u32* __restrict__ Kl,
                    const int* __restrict__ mfp, u64* __restrict__ keys)
{
    if (mfp[0] == 0) return;

    const int tid  = threadIdx.x;
    const int b    = blockIdx.x & 7;                      // XCD-affine batch
    const int lj   = (blockIdx.x >> 3) * 4 + (tid >> 6);  // local job 0..1087
    const int lane = tid & 63, lx = lane & 15, lg = lane >> 4;

    // decode: band a (16-row groups 8a..8a+7) has 8*(16-a) jobs
    int rem = lj;
    int a = 0;
    while (rem >= 8 * (16 - a)) { rem -= 8 * (16 - a); a++; }
    const int gl = rem / (16 - a);
    const int jj = rem - gl * (16 - a);
    const int g16 = 8 * a + gl;          // 16-row group 0..127
    const int m0  = 16 * g16;
    const int s0  = 128 * (a + jj);

    const f4 fz = {0.f, 0.f, 0.f, 0.f};
    f4 sa[8];
    #pragma unroll
    for (int nt = 0; nt < 8; nt++) sa[nt] = fz;

    // ---- main loop: fully unrolled, zero arrays, zero LDS, zero barriers ----
    const size_t rb = ((size_t)(b * SEQ + m0 + lx)) * 256;
    const size_t kb = ((size_t)(b * 64) * SEQ + s0 + lx) * 4;
    #pragma unroll
    for (int t = 0; t < 16; t++) {
        const h8 ah = __builtin_bit_cast(h8, *(const u4v*)(Qh + rb + 16 * t + 4 * lg));
        const h8 al = __builtin_bit_cast(h8, *(const u4v*)(Ql + rb + 16 * t + 4 * lg));
        const size_t rowoff = kb + (size_t)(4 * t + lg) * (SEQ * 4);
        #pragma unroll
        for (int nt = 0; nt < 8; nt++) {
            const h8 kh = __builtin_bit_cast(h8, *(const u4v*)(Kh + rowoff + 64 * nt));
            const h8 kl = __builtin_bit_cast(h8, *(const u4v*)(Kl + rowoff + 64 * nt));
            sa[nt] = MFMA16(ah, kh, sa[nt]);
            sa[nt] = MFMA16(ah, kl, sa[nt]);
            sa[nt] = MFMA16(al, kh, sa[nt]);
        }
    }

    // ---- NaN scrub (insurance) + masked argmin + atomicMin ----
    #pragma unroll
    for (int nt = 0; nt < 8; nt++)
        #pragma unroll
        for (int r = 0; r < 4; r++) {
            float s = sa[nt][r];
            sa[nt][r] = (s == s) ? s : 0.0f;
        }
    #pragma unroll
    for (int r = 0; r < 4; r++) {
        const int tg = m0 + 4 * lg + r;
        float mv = INFINITY; int mi = -1;
        #pragma unroll
        for (int nt = 0; nt < 8; nt++) {
            const int sg = s0 + 16 * nt + lx;
            const float v = sa[nt][r];
            if (sg >= tg && v < mv) { mv = v; mi = sg; }
        }
        #pragma unroll
        for (int off = 1; off < 16; off <<= 1) {
            const float ov = __shfl_xor(mv, off);
            const int   oi = __shfl_xor(mi, off);
            if (ov < mv || (ov == mv && oi >= 0 && (mi < 0 || oi < mi))) { mv = ov; mi = oi; }
        }
        if (lx == 0 && mi >= 0) {
            const u64 pk = ((u64)fkey(mv) << 32) | (u32)mi;
            atomicMin(&keys[(size_t)b * SEQ + tg], pk);
        }
    }
}

// ================= argmin_lds: R11-verbatim fallback (small ws) =================
__global__ __launch_bounds__(512, 2)
void argmin_lds_kernel(const float* __restrict__ Q, const float* __restrict__ K,
                       const int* __restrict__ mfp, u64* __restrict__ ws)
{
    if (mfp[0] == 0) return;
    __shared__ u32 KTh[2][128][32];
    __shared__ u32 KTl[2][128][32];
    __shared__ float sx[128][68];

    const int tid  = threadIdx.x;
    const int w    = tid >> 6, wp = w & 3, h = w >> 2;
    const int lane = tid & 63, lx = lane & 15, lg = lane >> 4;

    int j = blockIdx.x;
    const int b = j / 272; j -= b * 272;
    int mg = 0;
    while (true) { const int n = 16 - (mg >> 1); if (j < n) break; j -= n; mg++; }
    const int m0 = mg * 64;
    const int s0 = (m0 & ~127) + 128 * j;

    const float* __restrict__ Qb = Q + (size_t)b * SEQ * DIM;
    const float* __restrict__ Kb = K + (size_t)b * SEQ * DIM;
    const int krow = (tid >> 1) & 127;
    const int ksc  = tid & 1;

    h8 qh[8], ql[8];
    {
        const float* qrowp = Qb + (size_t)(m0 + 16 * wp + lx) * DIM;
        #pragma unroll
        for (int t = 0; t < 8; t++) {
            float bufv[8];
            *(f4*)&bufv[0] = *(const f4*)(qrowp + 256 * h + 32 * t + 8 * lg);
            *(f4*)&bufv[4] = *(const f4*)(qrowp + 256 * h + 32 * t + 8 * lg + 4);
            u4v uh, ul;
            #pragma unroll
            for (int p = 0; p < 4; p++) {
                const HL hl = split2t(bufv[2*p], bufv[2*p+1]);
                uh[p] = hl.hi; ul[p] = hl.lo;
            }
            qh[t] = __builtin_bit_cast(h8, uh);
            ql[t] = __builtin_bit_cast(h8, ul);
        }
    }
    const f4 fz = {0.f, 0.f, 0.f, 0.f};
    f4 sa[8];
    #pragma unroll
    for (int nt = 0; nt < 8; nt++) sa[nt] = fz;

    f4 kreg[8];
    #pragma unroll
    for (int c = 0; c < 8; c++)
        kreg[c] = *(const f4*)(Kb + (size_t)(s0 + krow) * DIM + 256 * h + 32 * ksc + 4 * c);

    #pragma unroll
    for (int i = 0; i < 4; i++) {
        if (i) __syncthreads();
        {
            u32 HH[16], LL[16];
            #pragma unroll
            for (int c = 0; c < 8; c++) {
                const HL e0 = split2t(kreg[c][0], kreg[c][1]);
                const HL e1 = split2t(kreg[c][2], kreg[c][3]);
                HH[2*c] = e0.hi;   LL[2*c] = e0.lo;
                HH[2*c+1] = e1.hi; LL[2*c+1] = e1.lo;
            }
            #pragma unroll
            for (int qd = 0; qd < 4; qd++) {
                const int gp = ((4 * ksc + qd) ^ (krow & 7)) * 4;
                u4v vh = {HH[4*qd], HH[4*qd+1], HH[4*qd+2], HH[4*qd+3]};
                u4v vl = {LL[4*qd], LL[4*qd+1], LL[4*qd+2], LL[4*qd+3]};
                *(u4v*)&KTh[h][krow][gp] = vh;
                *(u4v*)&KTl[h][krow][gp] = vl;
            }
        }
        __syncthreads();
        if (i < 3) {
            #pragma unroll
            for (int c = 0; c < 8; c++)
                kreg[c] = *(const f4*)(Kb + (size_t)(s0 + krow) * DIM
                                       + 256 * h + 64 * (i + 1) + 32 * ksc + 4 * c);
        }
        __builtin_amdgcn_s_setprio(1);
        #pragma unroll
        for (int tl = 0; tl < 2; tl++) {
            const int t = 2 * i + tl;
            #pragma unroll
            for (int nt = 0; nt < 8; nt++) {
                const int s  = 16 * nt + lx;
                const int gp = ((4 * tl + lg) ^ (s & 7)) * 4;
                const h8 kh = __builtin_bit_cast(h8, *(const u4v*)&KTh[h][s][gp]);
                const h8 kl = __builtin_bit_cast(h8, *(const u4v*)&KTl[h][s][gp]);
                sa[nt] = MFMA16(qh[t], kh, sa[nt]);
                sa[nt] = MFMA16(qh[t], kl, sa[nt]);
                sa[nt] = MFMA16(ql[t], kh, sa[nt]);
            }
        }
        __builtin_amdgcn_s_setprio(0);
    }

    if (h == 0) {
        #pragma unroll
        for (int nt = 0; nt < 8; nt++)
            *(f4*)&sx[16 * nt + lx][16 * wp + 4 * lg] = sa[nt];
    }
    __syncthreads();
    if (h == 1) {
        #pragma unroll
        for (int nt = 0; nt < 8; nt++) {
            const f4 part = *(const f4*)&sx[16 * nt + lx][16 * wp + 4 * lg];
            #pragma unroll
            for (int r = 0; r < 4; r++) {
                float s = sa[nt][r] + part[r];
                sa[nt][r] = (s == s) ? s : 0.0f;
            }
        }
        #pragma unroll
        for (int r = 0; r < 4; r++) {
            const int tg = m0 + 16 * wp + 4 * lg + r;
            float mv = INFINITY; int mi = -1;
            #pragma unroll
            for (int nt = 0; nt < 8; nt++) {
                const int sg = s0 + 16 * nt + lx;
                const float v = sa[nt][r];
                if (sg >= tg && v < mv) { mv = v; mi = sg; }
            }
            #pragma unroll
            for (int off = 1; off < 16; off <<= 1) {
                const float ov = __shfl_xor(mv, off);
                const int   oi = __shfl_xor(mi, off);
                if (ov < mv || (ov == mv && oi >= 0 && (mi < 0 || oi < mi))) { mv = ov; mi = oi; }
            }
            if (lx == 0 && mi >= 0) {
                const u64 pk = ((u64)fkey(mv) << 32) | (u32)mi;
                atomicMin(&ws[(size_t)b * SEQ + tg], pk);
            }
        }
    }
}

// ================= gather + worklist (R10-verbatim) =================
__global__ __launch_bounds__(512, 2)
void gather_kernel(const float* __restrict__ V, const u64* __restrict__ keys,
                   u32* __restrict__ cnt, u32* __restrict__ list,
                   float* __restrict__ Out)
{
    const int tid  = threadIdx.x;
    const int w    = tid >> 6;
    const int lane = tid & 63;
    const int b    = blockIdx.x >> 5;
    const int m0   = (blockIdx.x & 31) * 64;

    const float* __restrict__ Vb = V + (size_t)b * SEQ * DIM;
    float* __restrict__ Ob = Out + (size_t)b * SEQ * DIM;

    #pragma unroll
    for (int rr = 0; rr < 8; rr++) {
        const int tg = m0 + 8 * w + rr;
        const u64 pk = keys[(size_t)b * SEQ + tg];
        const u32 key = (u32)(pk >> 32);
        if (key < 0x80000000u) {
            const int ss = (int)(pk & 0xFFFFFFFFu);
            #pragma unroll
            for (int it = 0; it < 2; it++) {
                const int col = 256 * it + 4 * lane;
                *(f4*)(Ob + (size_t)tg * DIM + col) = *(const f4*)(Vb + (size_t)ss * DIM + col);
            }
        } else if (lane == 0) {
            const u32 p = atomicAdd(cnt, 1u);
            list[p] = ((u32)b << 16) | (u32)tg;
        }
    }
}

// ====== fb_part (R11-verbatim) ======
__global__ __launch_bounds__(512, 2)
void fb_part_kernel(const float* __restrict__ Q, const float* __restrict__ K,
                    const float* __restrict__ V, const int* __restrict__ mfp,
                    const u32* __restrict__ cnt, const u32* __restrict__ list,
                    float2* __restrict__ meta, float* __restrict__ partials)
{
    __shared__ float qrow[DIM];
    __shared__ float zpart[4][CHW];
    __shared__ float zs[CHW];
    __shared__ float zp[CHW];
    __shared__ f4    pacc[4][128];
    __shared__ float red2[2];

    const int tid = threadIdx.x;
    const int mf  = mfp[0];
    const float dk = 22.627416997969522f;

    const int n  = (int)cnt[0];
    const int nw = min(n * NCH, CAP);

    for (int wi = blockIdx.x; wi < nw; wi += gridDim.x) {
        const int ridx  = wi >> 4;
        const int chunk = wi & 15;
        const u32 e  = list[ridx];
        const int b  = (int)(e >> 16);
        const int tg = (int)(e & 0xFFFFu);

        const float* __restrict__ Qb = Q + (size_t)b * SEQ * DIM;
        const float* __restrict__ Kb = K + (size_t)b * SEQ * DIM;
        const float* __restrict__ Vb = V + (size_t)b * SEQ * DIM;

        if (tid < 128) *(f4*)&qrow[4 * tid] = *(const f4*)(Qb + (size_t)tg * DIM + 4 * tid);
        __syncthreads();
        {
            const int jj   = tid & 127;
            const int dseg = tid >> 7;
            const int col  = chunk * CHW + jj;
            const float* kr = Kb + (size_t)col * DIM + 128 * dseg;
            float acc = 0.f;
            #pragma unroll 8
            for (int d4 = 0; d4 < 32; d4++) {
                const f4 q = *(const f4*)&qrow[4 * (32 * dseg + d4)];
                const f4 k = *(const f4*)(kr + 4 * d4);
                acc += q[0]*k[0] + q[1]*k[1] + q[2]*k[2] + q[3]*k[3];
            }
            zpart[dseg][jj] = acc;
        }
        __syncthreads();
        if (tid < 128) {
            const int col = chunk * CHW + tid;
            float z = zpart[0][tid] + zpart[1][tid] + zpart[2][tid] + zpart[3][tid];
            const float mult = (mf && col >= tg) ? -1.0e9f : 1.0f;
            zs[tid] = z * mult / dk;
        }
        __syncthreads();
        if (tid < 64) {
            float m = fmaxf(zs[tid], zs[tid + 64]);
            #pragma unroll
            for (int off = 1; off < 64; off <<= 1) m = fmaxf(m, __shfl_xor(m, off));
            if (tid == 0) red2[0] = m;
        }
        __syncthreads();
        const float M = red2[0];
        if (tid < 128) zp[tid] = expf(zs[tid] - M);
        __syncthreads();
        if (tid < 64) {
            float s = zp[tid] + zp[tid + 64];
            #pragma unroll
            for (int off = 1; off < 64; off <<= 1) s += __shfl_xor(s, off);
            if (tid == 0) red2[1] = s;
        }
        {
            const int dq   = tid & 127;
            const int sseg = tid >> 7;
            f4 acc = {0.f, 0.f, 0.f, 0.f};
            const int sb = chunk * CHW + 32 * sseg;
            #pragma unroll 8
            for (int s = 0; s < 32; s++)
                acc += zp[32 * sseg + s] * *(const f4*)(Vb + (size_t)(sb + s) * DIM + 4 * dq);
            pacc[sseg][dq] = acc;
        }
        __syncthreads();
        if (tid < 128) {
            const f4 nc = pacc[0][tid] + pacc[1][tid] + pacc[2][tid] + pacc[3][tid];
            *(f4*)&partials[(size_t)wi * DIM + 4 * tid] = nc;
        }
        if (tid == 0) meta[wi] = make_float2(M, red2[1]);
        __syncthreads();
    }
}

// ====== fb_combine (R11-verbatim) ======
__global__ __launch_bounds__(512, 2)
void fb_combine_kernel(const float* __restrict__ Q, const float* __restrict__ K,
                       const float* __restrict__ V, const int* __restrict__ mfp,
                       const u32* __restrict__ cnt, const u32* __restrict__ list,
                       const float2* __restrict__ meta, const float* __restrict__ partials,
                       float* __restrict__ Out)
{
    __shared__ float qrow[DIM];
    __shared__ float zrow[SEQ];
    __shared__ float red[8];
    __shared__ f4    pacc[4][128];

    const int tid  = threadIdx.x;
    const int w    = tid >> 6;
    const int lane = tid & 63;
    const int mf   = mfp[0];
    const float dk = 22.627416997969522f;

    const int n = (int)cnt[0];
    for (int idx = blockIdx.x; idx < n; idx += gridDim.x) {
        const u32 e  = list[idx];
        const int b  = (int)(e >> 16);
        const int tg = (int)(e & 0xFFFFu);
        float* __restrict__ Ob = Out + (size_t)b * SEQ * DIM;

        if (idx < CAP / NCH) {
            float M = -INFINITY;
            #pragma unroll
            for (int c = 0; c < NCH; c++) M = fmaxf(M, meta[idx * NCH + c].x);
            float L = 0.f, o = 0.f;
            #pragma unroll
            for (int c = 0; c < NCH; c++) {
                const float2 mc = meta[idx * NCH + c];
                const float fct = expf(mc.x - M);
                L += mc.y * fct;
                o += partials[(size_t)(idx * NCH + c) * DIM + tid] * fct;
            }
            Ob[(size_t)tg * DIM + tid] = o / L;
        } else {
            const float* __restrict__ Qb = Q + (size_t)b * SEQ * DIM;
            const float* __restrict__ Kb = K + (size_t)b * SEQ * DIM;
            const float* __restrict__ Vb = V + (size_t)b * SEQ * DIM;
            if (tid < 128) *(f4*)&qrow[4 * tid] = *(const f4*)(Qb + (size_t)tg * DIM + 4 * tid);
            __syncthreads();
            float z4[4];
            #pragma unroll
            for (int c4 = 0; c4 < 4; c4++) {
                const int col = tid + 512 * c4;
                const float* kr = Kb + (size_t)col * DIM;
                float acc = 0.f;
                #pragma unroll 4
                for (int d4 = 0; d4 < 128; d4++) {
                    const f4 q = *(const f4*)&qrow[4 * d4];
                    const f4 k = *(const f4*)(kr + 4 * d4);
                    acc += q[0]*k[0] + q[1]*k[1] + q[2]*k[2] + q[3]*k[3];
                }
                const float mult = (mf && col >= tg) ? -1.0e9f : 1.0f;
                z4[c4] = acc * mult / dk;
            }
            float lm = fmaxf(fmaxf(z4[0], z4[1]), fmaxf(z4[2], z4[3]));
            #pragma unroll
            for (int off = 1; off < 64; off <<= 1) lm = fmaxf(lm, __shfl_xor(lm, off));
            if (lane == 0) red[w] = lm;
            __syncthreads();
            float M = red[0];
            #pragma unroll
            for (int i = 1; i < 8; i++) M = fmaxf(M, red[i]);
            float ls = 0.f;
            #pragma unroll
            for (int c4 = 0; c4 < 4; c4++) {
                const float p = expf(z4[c4] - M);
                zrow[tid + 512 * c4] = p;
                ls += p;
            }
            #pragma unroll
            for (int off = 1; off < 64; off <<= 1) ls += __shfl_xor(ls, off);
            __syncthreads();
            if (lane == 0) red[w] = ls;
            __syncthreads();
            float L = 0.f;
            #pragma unroll
            for (int i = 0; i < 8; i++) L += red[i];
            const int dq = tid & 127;
            const int sq = tid >> 7;
            f4 acc = {0.f, 0.f, 0.f, 0.f};
            const int sbeg = 512 * sq;
            #pragma unroll 8
            for (int s = 0; s < 512; s++)
                acc += zrow[sbeg + s] * *(const f4*)(Vb + (size_t)(sbeg + s) * DIM + 4 * dq);
            pacc[sq][dq] = acc;
            __syncthreads();
            if (tid < 128) {
                f4 r = pacc[0][tid] + pacc[1][tid] + pacc[2][tid] + pacc[3][tid];
                const float il = 1.0f / L;
                r[0] *= il; r[1] *= il; r[2] *= il; r[3] *= il;
                *(f4*)(Ob + (size_t)tg * DIM + 4 * tid) = r;
            }
            __syncthreads();
        }
    }
}

extern "C" void kernel_launch(void* const* d_in, const int* in_sizes, int n_in,
                              void* d_out, int out_size, void* d_ws, size_t ws_size,
                              hipStream_t stream) {
    const float* Q  = (const float*)d_in[0];
    const float* K  = (const float*)d_in[1];
    const float* V  = (const float*)d_in[2];
    const int*   mf = (const int*)d_in[3];
    float* O = (float*)d_out;

    char* wsb = (char*)d_ws;
    u64*    keys     = (u64*)wsb;                                   // 128 KB
    u32*    cnt      = (u32*)(wsb + 131072);
    u32*    list     = (u32*)(wsb + 131072 + 256);                  // 64 KB
    float2* meta     = (float2*)(wsb + 131072 + 256 + 65536);       // 4 KB
    float*  partials = (float*)(wsb + 131072 + 256 + 65536 + 8192); // 1 MB

    const size_t SPLIT_OFF = 1310720;                 // 1.25 MB, 16B-aligned
    const size_t ARR = (size_t)BATCH * SEQ * 256 * 4; // 16 MB per array
    u32* Qh = (u32*)(wsb + SPLIT_OFF);
    u32* Ql = (u32*)(wsb + SPLIT_OFF + ARR);
    u32* Kh = (u32*)(wsb + SPLIT_OFF + 2 * ARR);
    u32* Kl = (u32*)(wsb + SPLIT_OFF + 3 * ARR);
    const bool big_ws = ws_size >= SPLIT_OFF + 4 * ARR;

    hipMemsetAsync(keys, 0xFF, (size_t)BATCH * SEQ * sizeof(u64), stream);
    hipMemsetAsync(cnt, 0, sizeof(u32), stream);

    if (big_ws) {
        prep_q_kernel<<<dim3(4096), dim3(256), 0, stream>>>(Q, Qh, Ql);
        prep_k_kernel<<<dim3(512),  dim3(256), 0, stream>>>(K, Kh, Kl);
        argmin2_kernel<<<dim3(2176), dim3(256), 0, stream>>>(Qh, Ql, Kh, Kl, mf, keys);
    } else {
        argmin_lds_kernel<<<dim3(BATCH * 272), dim3(512), 0, stream>>>(Q, K, mf, keys);
    }
    gather_kernel<<<dim3(BATCH * (SEQ / 64)), dim3(512), 0, stream>>>(V, keys, cnt, list, O);
    fb_part_kernel<<<dim3(512), dim3(512), 0, stream>>>(Q, K, V, mf, cnt, list, meta, partials);
    fb_combine_kernel<<<dim3(128), dim3(512), 0, stream>>>(Q, K, V, mf, cnt, list, meta, partials, O);
}

// Round 16
// 180.543 us; speedup vs baseline: 1.5924x; 1.0346x over previous
//
#include <hip/hip_runtime.h>
#include <math.h>

#define BATCH 8
#define SEQ   2048
#define DIM   512
#define NCH   16
#define CHW   128
#define CAP   512

typedef unsigned int u32;
typedef unsigned long long u64;
typedef _Float16 h2  __attribute__((ext_vector_type(2)));
typedef _Float16 h8  __attribute__((ext_vector_type(8)));
typedef float    f4  __attribute__((ext_vector_type(4)));
typedef u32      u4v __attribute__((ext_vector_type(4)));

#define MFMA16(a,b,c) __builtin_amdgcn_mfma_f32_16x16x32_f16((a),(b),(c),0,0,0)

struct HL { u32 hi, lo; };
__device__ __forceinline__ HL split2t(float a, float b) {
    _Float16 ha = (_Float16)a, hb = (_Float16)b;
    h2 th; th[0] = ha; th[1] = hb;
    h2 tl; tl[0] = (_Float16)(a - (float)ha); tl[1] = (_Float16)(b - (float)hb);
    HL r; r.hi = __builtin_bit_cast(u32, th); r.lo = __builtin_bit_cast(u32, tl);
    return r;
}
__device__ __forceinline__ u32 fkey(float f) {
    u32 v = __builtin_bit_cast(u32, f);
    return (v & 0x80000000u) ? ~v : (v | 0x80000000u);
}

// ============ prep_q: Q -> hi/lo f16 pairs, layout [b][row][d-pair] ============
__global__ __launch_bounds__(256, 4)
void prep_q_kernel(const float* __restrict__ Q, u32* __restrict__ Qh, u32* __restrict__ Ql)
{
    const int gidx = blockIdx.x * 256 + threadIdx.x;   // (b, row, 8-d chunk c)
    const int c   = gidx & 63;
    const int row = (gidx >> 6) & 2047;
    const int b   = gidx >> 17;
    const float* src = Q + ((size_t)(b * SEQ + row)) * DIM + 8 * c;
    const f4 r0 = *(const f4*)(src);
    const f4 r1 = *(const f4*)(src + 4);
    const HL p0 = split2t(r0[0], r0[1]);
    const HL p1 = split2t(r0[2], r0[3]);
    const HL p2 = split2t(r1[0], r1[1]);
    const HL p3 = split2t(r1[2], r1[3]);
    u4v vh = {p0.hi, p1.hi, p2.hi, p3.hi};
    u4v vl = {p0.lo, p1.lo, p2.lo, p3.lo};
    const size_t off = ((size_t)(b * SEQ + row)) * 256 + 4 * c;
    *(u4v*)(Qh + off) = vh;
    *(u4v*)(Ql + off) = vl;
}

// ==== prep_k: K -> hi/lo f16 pairs, fragment-native K^T layout [b][g][s][4] ====
__global__ __launch_bounds__(256, 4)
void prep_k_kernel(const float* __restrict__ K, u32* __restrict__ Kh, u32* __restrict__ Kl)
{
    const int b = blockIdx.x >> 6;       // 8 batches
    const int g = blockIdx.x & 63;       // d-pair group (8 d per group)
    #pragma unroll
    for (int i = 0; i < 8; i++) {
        const int s = 256 * i + threadIdx.x;
        const float* src = K + ((size_t)(b * SEQ + s)) * DIM + 8 * g;
        const f4 r0 = *(const f4*)(src);
        const f4 r1 = *(const f4*)(src + 4);
        const HL p0 = split2t(r0[0], r0[1]);
        const HL p1 = split2t(r0[2], r0[3]);
        const HL p2 = split2t(r1[0], r1[1]);
        const HL p3 = split2t(r1[2], r1[3]);
        u4v vh = {p0.hi, p1.hi, p2.hi, p3.hi};
        u4v vl = {p0.lo, p1.lo, p2.lo, p3.lo};
        const size_t off = ((size_t)(b * 64 + g) * SEQ + s) * 4;
        *(u4v*)(Kh + off) = vh;   // coalesced: consecutive s -> consecutive 16B
        *(u4v*)(Kl + off) = vl;
    }
}

// ===== argmin2: one wave = one (64-row group, s-tile) job; K reused 4x =====
// R16: sa[4][8] accum (static idx, full unroll), 12 MFMAs per K-fragment load.
// Maps (R5-R15 validated): A row=lane&15, slot e<->k=8lg+e; B col=lane&15 same;
// C/D row=4lg+reg, col=lane&15.
__global__ __launch_bounds__(256, 2)
void argmin2_kernel(const u32* __restrict__ Qh, const u32* __restrict__ Ql,
                    const u32* __restrict__ Kh, const u32* __restrict__ Kl,
                    const int* __restrict__ mfp, u64* __restrict__ keys)
{
    if (mfp[0] == 0) return;

    const int tid  = threadIdx.x;
    const int b    = blockIdx.x & 7;                      // XCD-affine batch
    const int lj   = (blockIdx.x >> 3) * 4 + (tid >> 6);  // local job 0..271
    const int lane = tid & 63, lx = lane & 15, lg = lane >> 4;

    // decode: 64-row band mg has n = 16-(mg>>1) tiles (272 jobs/batch)
    int rem = lj;
    int mg = 0;
    while (rem >= 16 - (mg >> 1)) { rem -= 16 - (mg >> 1); mg++; }
    const int m0 = 64 * mg;
    const int s0 = 128 * ((mg >> 1) + rem);

    const f4 fz = {0.f, 0.f, 0.f, 0.f};
    f4 sa[4][8];
    #pragma unroll
    for (int rg = 0; rg < 4; rg++)
        #pragma unroll
        for (int nt = 0; nt < 8; nt++) sa[rg][nt] = fz;

    // ---- main loop: fully unrolled, no LDS, no barriers; K frag -> 12 MFMAs ----
    const size_t rb0 = ((size_t)(b * SEQ + m0 + lx)) * 256;   // rg stride = 4096
    const size_t kb  = ((size_t)(b * 64) * SEQ + s0 + lx) * 4;
    #pragma unroll
    for (int t = 0; t < 16; t++) {
        h8 ah[4], al[4];
        #pragma unroll
        for (int rg = 0; rg < 4; rg++) {
            ah[rg] = __builtin_bit_cast(h8, *(const u4v*)(Qh + rb0 + rg * 4096 + 16 * t + 4 * lg));
            al[rg] = __builtin_bit_cast(h8, *(const u4v*)(Ql + rb0 + rg * 4096 + 16 * t + 4 * lg));
        }
        const size_t rowoff = kb + (size_t)(4 * t + lg) * (SEQ * 4);
        #pragma unroll
        for (int nt = 0; nt < 8; nt++) {
            const h8 kh = __builtin_bit_cast(h8, *(const u4v*)(Kh + rowoff + 64 * nt));
            const h8 kl = __builtin_bit_cast(h8, *(const u4v*)(Kl + rowoff + 64 * nt));
            #pragma unroll
            for (int rg = 0; rg < 4; rg++) {
                sa[rg][nt] = MFMA16(ah[rg], kh, sa[rg][nt]);
                sa[rg][nt] = MFMA16(ah[rg], kl, sa[rg][nt]);
                sa[rg][nt] = MFMA16(al[rg], kh, sa[rg][nt]);
            }
        }
    }

    // ---- NaN scrub (insurance) + masked argmin + atomicMin (per 16-row grp) ----
    #pragma unroll
    for (int rg = 0; rg < 4; rg++) {
        #pragma unroll
        for (int nt = 0; nt < 8; nt++)
            #pragma unroll
            for (int r = 0; r < 4; r++) {
                float s = sa[rg][nt][r];
                sa[rg][nt][r] = (s == s) ? s : 0.0f;
            }
        #pragma unroll
        for (int r = 0; r < 4; r++) {
            const int tg = m0 + 16 * rg + 4 * lg + r;
            float mv = INFINITY; int mi = -1;
            #pragma unroll
            for (int nt = 0; nt < 8; nt++) {
                const int sg = s0 + 16 * nt + lx;
                const float v = sa[rg][nt][r];
                if (sg >= tg && v < mv) { mv = v; mi = sg; }
            }
            #pragma unroll
            for (int off = 1; off < 16; off <<= 1) {
                const float ov = __shfl_xor(mv, off);
                const int   oi = __shfl_xor(mi, off);
                if (ov < mv || (ov == mv && oi >= 0 && (mi < 0 || oi < mi))) { mv = ov; mi = oi; }
            }
            if (lx == 0 && mi >= 0) {
                const u64 pk = ((u64)fkey(mv) << 32) | (u32)mi;
                atomicMin(&keys[(size_t)b * SEQ + tg], pk);
            }
        }
    }
}

// ================= argmin_lds: R11-verbatim fallback (small ws) =================
__global__ __launch_bounds__(512, 2)
void argmin_lds_kernel(const float* __restrict__ Q, const float* __restrict__ K,
                       const int* __restrict__ mfp, u64* __restrict__ ws)
{
    if (mfp[0] == 0) return;
    __shared__ u32 KTh[2][128][32];
    __shared__ u32 KTl[2][128][32];
    __shared__ float sx[128][68];

    const int tid  = threadIdx.x;
    const int w    = tid >> 6, wp = w & 3, h = w >> 2;
    const int lane = tid & 63, lx = lane & 15, lg = lane >> 4;

    int j = blockIdx.x;
    const int b = j / 272; j -= b * 272;
    int mg = 0;
    while (true) { const int n = 16 - (mg >> 1); if (j < n) break; j -= n; mg++; }
    const int m0 = mg * 64;
    const int s0 = (m0 & ~127) + 128 * j;

    const float* __restrict__ Qb = Q + (size_t)b * SEQ * DIM;
    const float* __restrict__ Kb = K + (size_t)b * SEQ * DIM;
    const int krow = (tid >> 1) & 127;
    const int ksc  = tid & 1;

    h8 qh[8], ql[8];
    {
        const float* qrowp = Qb + (size_t)(m0 + 16 * wp + lx) * DIM;
        #pragma unroll
        for (int t = 0; t < 8; t++) {
            float bufv[8];
            *(f4*)&bufv[0] = *(const f4*)(qrowp + 256 * h + 32 * t + 8 * lg);
            *(f4*)&bufv[4] = *(const f4*)(qrowp + 256 * h + 32 * t + 8 * lg + 4);
            u4v uh, ul;
            #pragma unroll
            for (int p = 0; p < 4; p++) {
                const HL hl = split2t(bufv[2*p], bufv[2*p+1]);
                uh[p] = hl.hi; ul[p] = hl.lo;
            }
            qh[t] = __builtin_bit_cast(h8, uh);
            ql[t] = __builtin_bit_cast(h8, ul);
        }
    }
    const f4 fz = {0.f, 0.f, 0.f, 0.f};
    f4 sa[8];
    #pragma unroll
    for (int nt = 0; nt < 8; nt++) sa[nt] = fz;

    f4 kreg[8];
    #pragma unroll
    for (int c = 0; c < 8; c++)
        kreg[c] = *(const f4*)(Kb + (size_t)(s0 + krow) * DIM + 256 * h + 32 * ksc + 4 * c);

    #pragma unroll
    for (int i = 0; i < 4; i++) {
        if (i) __syncthreads();
        {
            u32 HH[16], LL[16];
            #pragma unroll
            for (int c = 0; c < 8; c++) {
                const HL e0 = split2t(kreg[c][0], kreg[c][1]);
                const HL e1 = split2t(kreg[c][2], kreg[c][3]);
                HH[2*c] = e0.hi;   LL[2*c] = e0.lo;
                HH[2*c+1] = e1.hi; LL[2*c+1] = e1.lo;
            }
            #pragma unroll
            for (int qd = 0; qd < 4; qd++) {
                const int gp = ((4 * ksc + qd) ^ (krow & 7)) * 4;
                u4v vh = {HH[4*qd], HH[4*qd+1], HH[4*qd+2], HH[4*qd+3]};
                u4v vl = {LL[4*qd], LL[4*qd+1], LL[4*qd+2], LL[4*qd+3]};
                *(u4v*)&KTh[h][krow][gp] = vh;
                *(u4v*)&KTl[h][krow][gp] = vl;
            }
        }
        __syncthreads();
        if (i < 3) {
            #pragma unroll
            for (int c = 0; c < 8; c++)
                kreg[c] = *(const f4*)(Kb + (size_t)(s0 + krow) * DIM
                                       + 256 * h + 64 * (i + 1) + 32 * ksc + 4 * c);
        }
        __builtin_amdgcn_s_setprio(1);
        #pragma unroll
        for (int tl = 0; tl < 2; tl++) {
            const int t = 2 * i + tl;
            #pragma unroll
            for (int nt = 0; nt < 8; nt++) {
                const int s  = 16 * nt + lx;
                const int gp = ((4 * tl + lg) ^ (s & 7)) * 4;
                const h8 kh = __builtin_bit_cast(h8, *(const u4v*)&KTh[h][s][gp]);
                const h8 kl = __builtin_bit_cast(h8, *(const u4v*)&KTl[h][s][gp]);
                sa[nt] = MFMA16(qh[t], kh, sa[nt]);
                sa[nt] = MFMA16(qh[t], kl, sa[nt]);
                sa[nt] = MFMA16(ql[t], kh, sa[nt]);
            }
        }
        __builtin_amdgcn_s_setprio(0);
    }

    if (h == 0) {
        #pragma unroll
        for (int nt = 0; nt < 8; nt++)
            *(f4*)&sx[16 * nt + lx][16 * wp + 4 * lg] = sa[nt];
    }
    __syncthreads();
    if (h == 1) {
        #pragma unroll
        for (int nt = 0; nt < 8; nt++) {
            const f4 part = *(const f4*)&sx[16 * nt + lx][16 * wp + 4 * lg];
            #pragma unroll
            for (int r = 0; r < 4; r++) {
                float s = sa[nt][r] + part[r];
                sa[nt][r] = (s == s) ? s : 0.0f;
            }
        }
        #pragma unroll
        for (int r = 0; r < 4; r++) {
            const int tg = m0 + 16 * wp + 4 * lg + r;
            float mv = INFINITY; int mi = -1;
            #pragma unroll
            for (int nt = 0; nt < 8; nt++) {
                const int sg = s0 + 16 * nt + lx;
                const float v = sa[nt][r];
                if (sg >= tg && v < mv) { mv = v; mi = sg; }
            }
            #pragma unroll
            for (int off = 1; off < 16; off <<= 1) {
                const float ov = __shfl_xor(mv, off);
                const int   oi = __shfl_xor(mi, off);
                if (ov < mv || (ov == mv && oi >= 0 && (mi < 0 || oi < mi))) { mv = ov; mi = oi; }
            }
            if (lx == 0 && mi >= 0) {
                const u64 pk = ((u64)fkey(mv) << 32) | (u32)mi;
                atomicMin(&ws[(size_t)b * SEQ + tg], pk);
            }
        }
    }
}

// ================= gather + worklist (R10-verbatim) =================
__global__ __launch_bounds__(512, 2)
void gather_kernel(const float* __restrict__ V, const u64* __restrict__ keys,
                   u32* __restrict__ cnt, u32* __restrict__ list,
                   float* __restrict__ Out)
{
    const int tid  = threadIdx.x;
    const int w    = tid >> 6;
    const int lane = tid & 63;
    const int b    = blockIdx.x >> 5;
    const int m0   = (blockIdx.x & 31) * 64;

    const float* __restrict__ Vb = V + (size_t)b * SEQ * DIM;
    float* __restrict__ Ob = Out + (size_t)b * SEQ * DIM;

    #pragma unroll
    for (int rr = 0; rr < 8; rr++) {
        const int tg = m0 + 8 * w + rr;
        const u64 pk = keys[(size_t)b * SEQ + tg];
        const u32 key = (u32)(pk >> 32);
        if (key < 0x80000000u) {
            const int ss = (int)(pk & 0xFFFFFFFFu);
            #pragma unroll
            for (int it = 0; it < 2; it++) {
                const int col = 256 * it + 4 * lane;
                *(f4*)(Ob + (size_t)tg * DIM + col) = *(const f4*)(Vb + (size_t)ss * DIM + col);
            }
        } else if (lane == 0) {
            const u32 p = atomicAdd(cnt, 1u);
            list[p] = ((u32)b << 16) | (u32)tg;
        }
    }
}

// ====== fb_part (R11-verbatim) ======
__global__ __launch_bounds__(512, 2)
void fb_part_kernel(const float* __restrict__ Q, const float* __restrict__ K,
                    const float* __restrict__ V, const int* __restrict__ mfp,
                    const u32* __restrict__ cnt, const u32* __restrict__ list,
                    float2* __restrict__ meta, float* __restrict__ partials)
{
    __shared__ float qrow[DIM];
    __shared__ float zpart[4][CHW];
    __shared__ float zs[CHW];
    __shared__ float zp[CHW];
    __shared__ f4    pacc[4][128];
    __shared__ float red2[2];

    const int tid = threadIdx.x;
    const int mf  = mfp[0];
    const float dk = 22.627416997969522f;

    const int n  = (int)cnt[0];
    const int nw = min(n * NCH, CAP);

    for (int wi = blockIdx.x; wi < nw; wi += gridDim.x) {
        const int ridx  = wi >> 4;
        const int chunk = wi & 15;
        const u32 e  = list[ridx];
        const int b  = (int)(e >> 16);
        const int tg = (int)(e & 0xFFFFu);

        const float* __restrict__ Qb = Q + (size_t)b * SEQ * DIM;
        const float* __restrict__ Kb = K + (size_t)b * SEQ * DIM;
        const float* __restrict__ Vb = V + (size_t)b * SEQ * DIM;

        if (tid < 128) *(f4*)&qrow[4 * tid] = *(const f4*)(Qb + (size_t)tg * DIM + 4 * tid);
        __syncthreads();
        {
            const int jj   = tid & 127;
            const int dseg = tid >> 7;
            const int col  = chunk * CHW + jj;
            const float* kr = Kb + (size_t)col * DIM + 128 * dseg;
            float acc = 0.f;
            #pragma unroll 8
            for (int d4 = 0; d4 < 32; d4++) {
                const f4 q = *(const f4*)&qrow[4 * (32 * dseg + d4)];
                const f4 k = *(const f4*)(kr + 4 * d4);
                acc += q[0]*k[0] + q[1]*k[1] + q[2]*k[2] + q[3]*k[3];
            }
            zpart[dseg][jj] = acc;
        }
        __syncthreads();
        if (tid < 128) {
            const int col = chunk * CHW + tid;
            float z = zpart[0][tid] + zpart[1][tid] + zpart[2][tid] + zpart[3][tid];
            const float mult = (mf && col >= tg) ? -1.0e9f : 1.0f;
            zs[tid] = z * mult / dk;
        }
        __syncthreads();
        if (tid < 64) {
            float m = fmaxf(zs[tid], zs[tid + 64]);
            #pragma unroll
            for (int off = 1; off < 64; off <<= 1) m = fmaxf(m, __shfl_xor(m, off));
            if (tid == 0) red2[0] = m;
        }
        __syncthreads();
        const float M = red2[0];
        if (tid < 128) zp[tid] = expf(zs[tid] - M);
        __syncthreads();
        if (tid < 64) {
            float s = zp[tid] + zp[tid + 64];
            #pragma unroll
            for (int off = 1; off < 64; off <<= 1) s += __shfl_xor(s, off);
            if (tid == 0) red2[1] = s;
        }
        {
            const int dq   = tid & 127;
            const int sseg = tid >> 7;
            f4 acc = {0.f, 0.f, 0.f, 0.f};
            const int sb = chunk * CHW + 32 * sseg;
            #pragma unroll 8
            for (int s = 0; s < 32; s++)
                acc += zp[32 * sseg + s] * *(const f4*)(Vb + (size_t)(sb + s) * DIM + 4 * dq);
            pacc[sseg][dq] = acc;
        }
        __syncthreads();
        if (tid < 128) {
            const f4 nc = pacc[0][tid] + pacc[1][tid] + pacc[2][tid] + pacc[3][tid];
            *(f4*)&partials[(size_t)wi * DIM + 4 * tid] = nc;
        }
        if (tid == 0) meta[wi] = make_float2(M, red2[1]);
        __syncthreads();
    }
}

// ====== fb_combine (R11-verbatim) ======
__global__ __launch_bounds__(512, 2)
void fb_combine_kernel(const float* __restrict__ Q, const float* __restrict__ K,
                       const float* __restrict__ V, const int* __restrict__ mfp,
                       const u32* __restrict__ cnt, const u32* __restrict__ list,
                       const float2* __restrict__ meta, const float* __restrict__ partials,
                       float* __restrict__ Out)
{
    __shared__ float qrow[DIM];
    __shared__ float zrow[SEQ];
    __shared__ float red[8];
    __shared__ f4    pacc[4][128];

    const int tid  = threadIdx.x;
    const int w    = tid >> 6;
    const int lane = tid & 63;
    const int mf   = mfp[0];
    const float dk = 22.627416997969522f;

    const int n = (int)cnt[0];
    for (int idx = blockIdx.x; idx < n; idx += gridDim.x) {
        const u32 e  = list[idx];
        const int b  = (int)(e >> 16);
        const int tg = (int)(e & 0xFFFFu);
        float* __restrict__ Ob = Out + (size_t)b * SEQ * DIM;

        if (idx < CAP / NCH) {
            float M = -INFINITY;
            #pragma unroll
            for (int c = 0; c < NCH; c++) M = fmaxf(M, meta[idx * NCH + c].x);
            float L = 0.f, o = 0.f;
            #pragma unroll
            for (int c = 0; c < NCH; c++) {
                const float2 mc = meta[idx * NCH + c];
                const float fct = expf(mc.x - M);
                L += mc.y * fct;
                o += partials[(size_t)(idx * NCH + c) * DIM + tid] * fct;
            }
            Ob[(size_t)tg * DIM + tid] = o / L;
        } else {
            const float* __restrict__ Qb = Q + (size_t)b * SEQ * DIM;
            const float* __restrict__ Kb = K + (size_t)b * SEQ * DIM;
            const float* __restrict__ Vb = V + (size_t)b * SEQ * DIM;
            if (tid < 128) *(f4*)&qrow[4 * tid] = *(const f4*)(Qb + (size_t)tg * DIM + 4 * tid);
            __syncthreads();
            float z4[4];
            #pragma unroll
            for (int c4 = 0; c4 < 4; c4++) {
                const int col = tid + 512 * c4;
                const float* kr = Kb + (size_t)col * DIM;
                float acc = 0.f;
                #pragma unroll 4
                for (int d4 = 0; d4 < 128; d4++) {
                    const f4 q = *(const f4*)&qrow[4 * d4];
                    const f4 k = *(const f4*)(kr + 4 * d4);
                    acc += q[0]*k[0] + q[1]*k[1] + q[2]*k[2] + q[3]*k[3];
                }
                const float mult = (mf && col >= tg) ? -1.0e9f : 1.0f;
                z4[c4] = acc * mult / dk;
            }
            float lm = fmaxf(fmaxf(z4[0], z4[1]), fmaxf(z4[2], z4[3]));
            #pragma unroll
            for (int off = 1; off < 64; off <<= 1) lm = fmaxf(lm, __shfl_xor(lm, off));
            if (lane == 0) red[w] = lm;
            __syncthreads();
            float M = red[0];
            #pragma unroll
            for (int i = 1; i < 8; i++) M = fmaxf(M, red[i]);
            float ls = 0.f;
            #pragma unroll
            for (int c4 = 0; c4 < 4; c4++) {
                const float p = expf(z4[c4] - M);
                zrow[tid + 512 * c4] = p;
                ls += p;
            }
            #pragma unroll
            for (int off = 1; off < 64; off <<= 1) ls += __shfl_xor(ls, off);
            __syncthreads();
            if (lane == 0) red[w] = ls;
            __syncthreads();
            float L = 0.f;
            #pragma unroll
            for (int i = 0; i < 8; i++) L += red[i];
            const int dq = tid & 127;
            const int sq = tid >> 7;
            f4 acc = {0.f, 0.f, 0.f, 0.f};
            const int sbeg = 512 * sq;
            #pragma unroll 8
            for (int s = 0; s < 512; s++)
                acc += zrow[sbeg + s] * *(const f4*)(Vb + (size_t)(sbeg + s) * DIM + 4 * dq);
            pacc[sq][dq] = acc;
            __syncthreads();
            if (tid < 128) {
                f4 r = pacc[0][tid] + pacc[1][tid] + pacc[2][tid] + pacc[3][tid];
                const float il = 1.0f / L;
                r[0] *= il; r[1] *= il; r[2] *= il; r[3] *= il;
                *(f4*)(Ob + (size_t)tg * DIM + 4 * tid) = r;
            }
            __syncthreads();
        }
    }
}

extern "C" void kernel_launch(void* const* d_in, const int* in_sizes, int n_in,
                              void* d_out, int out_size, void* d_ws, size_t ws_size,
                              hipStream_t stream) {
    const float* Q  = (const float*)d_in[0];
    const float* K  = (const float*)d_in[1];
    const float* V  = (const float*)d_in[2];
    const int*   mf = (const int*)d_in[3];
    float* O = (float*)d_out;

    char* wsb = (char*)d_ws;
    u64*    keys     = (u64*)wsb;                                   // 128 KB
    u32*    cnt      = (u32*)(wsb + 131072);
    u32*    list     = (u32*)(wsb + 131072 + 256);                  // 64 KB
    float2* meta     = (float2*)(wsb + 131072 + 256 + 65536);       // 4 KB
    float*  partials = (float*)(wsb + 131072 + 256 + 65536 + 8192); // 1 MB

    const size_t SPLIT_OFF = 1310720;                 // 1.25 MB, 16B-aligned
    const size_t ARR = (size_t)BATCH * SEQ * 256 * 4; // 16 MB per array
    u32* Qh = (u32*)(wsb + SPLIT_OFF);
    u32* Ql = (u32*)(wsb + SPLIT_OFF + ARR);
    u32* Kh = (u32*)(wsb + SPLIT_OFF + 2 * ARR);
    u32* Kl = (u32*)(wsb + SPLIT_OFF + 3 * ARR);
    const bool big_ws = ws_size >= SPLIT_OFF + 4 * ARR;

    hipMemsetAsync(keys, 0xFF, (size_t)BATCH * SEQ * sizeof(u64), stream);
    hipMemsetAsync(cnt, 0, sizeof(u32), stream);

    if (big_ws) {
        prep_q_kernel<<<dim3(4096), dim3(256), 0, stream>>>(Q, Qh, Ql);
        prep_k_kernel<<<dim3(512),  dim3(256), 0, stream>>>(K, Kh, Kl);
        argmin2_kernel<<<dim3(544), dim3(256), 0, stream>>>(Qh, Ql, Kh, Kl, mf, keys);
    } else {
        argmin_lds_kernel<<<dim3(BATCH * 272), dim3(512), 0, stream>>>(Q, K, mf, keys);
    }
    gather_kernel<<<dim3(BATCH * (SEQ / 64)), dim3(512), 0, stream>>>(V, keys, cnt, list, O);
    fb_part_kernel<<<dim3(512), dim3(512), 0, stream>>>(Q, K, V, mf, cnt, list, meta, partials);
    fb_combine_kernel<<<dim3(128), dim3(512), 0, stream>>>(Q, K, V, mf, cnt, list, meta, partials, O);
}

// Round 17
// 163.494 us; speedup vs baseline: 1.7584x; 1.1043x over previous
//
#include <hip/hip_runtime.h>
#include <math.h>

#define BATCH 8
#define SEQ   2048
#define DIM   512
#define NCH   16
#define CHW   128
#define CAP   512

typedef unsigned int u32;
typedef unsigned long long u64;
typedef _Float16 h2  __attribute__((ext_vector_type(2)));
typedef _Float16 h8  __attribute__((ext_vector_type(8)));
typedef float    f4  __attribute__((ext_vector_type(4)));
typedef u32      u4v __attribute__((ext_vector_type(4)));

#define MFMA16(a,b,c) __builtin_amdgcn_mfma_f32_16x16x32_f16((a),(b),(c),0,0,0)

struct HL { u32 hi, lo; };
__device__ __forceinline__ HL split2t(float a, float b) {
    _Float16 ha = (_Float16)a, hb = (_Float16)b;
    h2 th; th[0] = ha; th[1] = hb;
    h2 tl; tl[0] = (_Float16)(a - (float)ha); tl[1] = (_Float16)(b - (float)hb);
    HL r; r.hi = __builtin_bit_cast(u32, th); r.lo = __builtin_bit_cast(u32, tl);
    return r;
}
__device__ __forceinline__ u32 fkey(float f) {
    u32 v = __builtin_bit_cast(u32, f);
    return (v & 0x80000000u) ? ~v : (v | 0x80000000u);
}

// ==== prep_q2: Q -> hi/lo f16 pairs, FRAGMENT-NATIVE layout [b][g16][t][lane][4] ====
// A-frag for wave on 16-row group g16, k-window t: one contiguous 1KB load.
__global__ __launch_bounds__(256, 4)
void prep_q2_kernel(const float* __restrict__ Q, u32* __restrict__ Qh, u32* __restrict__ Ql)
{
    const int b    = blockIdx.x >> 7;     // 1024 blocks
    const int g16  = blockIdx.x & 127;
    const int lane = threadIdx.x & 63;
    const int tq   = threadIdx.x >> 6;
    const int lx   = lane & 15, lg = lane >> 4;
    const float* src0 = Q + ((size_t)(b * SEQ + g16 * 16 + lx)) * DIM + 8 * lg;
    #pragma unroll
    for (int p = 0; p < 4; p++) {
        const int t = p * 4 + tq;
        const float* s = src0 + 32 * t;
        const f4 r0 = *(const f4*)(s);
        const f4 r1 = *(const f4*)(s + 4);
        const HL p0 = split2t(r0[0], r0[1]);
        const HL p1 = split2t(r0[2], r0[3]);
        const HL p2 = split2t(r1[0], r1[1]);
        const HL p3 = split2t(r1[2], r1[3]);
        u4v vh = {p0.hi, p1.hi, p2.hi, p3.hi};
        u4v vl = {p0.lo, p1.lo, p2.lo, p3.lo};
        const size_t off = (((size_t)(b * 128 + g16) * 16 + t) * 256) + (size_t)lane * 4;
        *(u4v*)(Qh + off) = vh;   // writes: 64 lanes x 16B = contiguous 1KB
        *(u4v*)(Ql + off) = vl;
    }
}

// ==== prep_k2: K -> hi/lo pairs, FRAGMENT-NATIVE layout [b][st][t][nt][lane][4] ====
// B-frag for (s-tile st, k-window t, col-tile nt): one contiguous 1KB load.
__global__ __launch_bounds__(256, 4)
void prep_k2_kernel(const float* __restrict__ K, u32* __restrict__ Kh, u32* __restrict__ Kl)
{
    const int b    = blockIdx.x >> 8;     // 2048 blocks
    const int st   = (blockIdx.x >> 4) & 15;
    const int t    = blockIdx.x & 15;
    const int lane = threadIdx.x & 63;
    const int nq   = threadIdx.x >> 6;
    const int lx   = lane & 15, lg = lane >> 4;
    #pragma unroll
    for (int p = 0; p < 2; p++) {
        const int nt = p * 4 + nq;
        const float* s = K + ((size_t)(b * SEQ + 128 * st + 16 * nt + lx)) * DIM + 32 * t + 8 * lg;
        const f4 r0 = *(const f4*)(s);
        const f4 r1 = *(const f4*)(s + 4);
        const HL p0 = split2t(r0[0], r0[1]);
        const HL p1 = split2t(r0[2], r0[3]);
        const HL p2 = split2t(r1[0], r1[1]);
        const HL p3 = split2t(r1[2], r1[3]);
        u4v vh = {p0.hi, p1.hi, p2.hi, p3.hi};
        u4v vl = {p0.lo, p1.lo, p2.lo, p3.lo};
        const size_t off = ((((size_t)(b * 16 + st) * 16 + t) * 8 + nt) * 256) + (size_t)lane * 4;
        *(u4v*)(Kh + off) = vh;
        *(u4v*)(Kl + off) = vl;
    }
}

// ===== argmin3: block = (256-row group, s-tile); 4 waves SHARE the K stream =====
// Every fragment load is one contiguous 1KB segment. No LDS, no barriers.
// Maps (R5-R16 validated): A row=lane&15, slot e<->k=8lg+e; B col=lane&15 same;
// C/D row=4lg+reg, col=lane&15.
__global__ __launch_bounds__(256, 2)
void argmin3_kernel(const u32* __restrict__ Qh, const u32* __restrict__ Ql,
                    const u32* __restrict__ Kh, const u32* __restrict__ Kl,
                    const int* __restrict__ mfp, u64* __restrict__ keys)
{
    if (mfp[0] == 0) return;

    const int tid  = threadIdx.x;
    const int b    = blockIdx.x & 7;        // XCD-affine batch (72 jobs/batch)
    int rem        = blockIdx.x >> 3;       // 0..71
    const int w    = tid >> 6;
    const int lane = tid & 63, lx = lane & 15, lg = lane >> 4;

    // decode: 256-row band g2 (0..7) has 16-2*g2 tiles
    int g2 = 0;
    while (rem >= 16 - 2 * g2) { rem -= 16 - 2 * g2; g2++; }
    const int st   = 2 * g2 + rem;          // shared s-tile for all 4 waves
    const int s0   = 128 * st;
    const int g16b = g2 * 16 + w * 4;       // wave's first 16-row group
    const int m0   = 64 * (g2 * 4 + w);     // wave's first row

    const f4 fz = {0.f, 0.f, 0.f, 0.f};
    f4 sa[4][8];
    #pragma unroll
    for (int rg = 0; rg < 4; rg++)
        #pragma unroll
        for (int nt = 0; nt < 8; nt++) sa[rg][nt] = fz;

    const size_t qoff = ((size_t)(b * 128 + g16b) * 16) * 256 + (size_t)lane * 4;
    const size_t koff = ((size_t)(b * 16 + st) * 128) * 256 + (size_t)lane * 4;

    #pragma unroll
    for (int t = 0; t < 16; t++) {
        h8 ah[4], al[4];
        #pragma unroll
        for (int rg = 0; rg < 4; rg++) {
            ah[rg] = __builtin_bit_cast(h8, *(const u4v*)(Qh + qoff + (size_t)(rg * 16 + t) * 256));
            al[rg] = __builtin_bit_cast(h8, *(const u4v*)(Ql + qoff + (size_t)(rg * 16 + t) * 256));
        }
        #pragma unroll
        for (int nt = 0; nt < 8; nt++) {
            const h8 kh = __builtin_bit_cast(h8, *(const u4v*)(Kh + koff + (size_t)(t * 8 + nt) * 256));
            const h8 kl = __builtin_bit_cast(h8, *(const u4v*)(Kl + koff + (size_t)(t * 8 + nt) * 256));
            #pragma unroll
            for (int rg = 0; rg < 4; rg++) {
                sa[rg][nt] = MFMA16(ah[rg], kh, sa[rg][nt]);
                sa[rg][nt] = MFMA16(ah[rg], kl, sa[rg][nt]);
                sa[rg][nt] = MFMA16(al[rg], kh, sa[rg][nt]);
            }
        }
    }

    // ---- NaN scrub (insurance) + masked argmin + atomicMin (per 16-row grp) ----
    #pragma unroll
    for (int rg = 0; rg < 4; rg++) {
        #pragma unroll
        for (int nt = 0; nt < 8; nt++)
            #pragma unroll
            for (int r = 0; r < 4; r++) {
                float s = sa[rg][nt][r];
                sa[rg][nt][r] = (s == s) ? s : 0.0f;
            }
        #pragma unroll
        for (int r = 0; r < 4; r++) {
            const int tg = m0 + 16 * rg + 4 * lg + r;
            float mv = INFINITY; int mi = -1;
            #pragma unroll
            for (int nt = 0; nt < 8; nt++) {
                const int sg = s0 + 16 * nt + lx;
                const float v = sa[rg][nt][r];
                if (sg >= tg && v < mv) { mv = v; mi = sg; }
            }
            #pragma unroll
            for (int off = 1; off < 16; off <<= 1) {
                const float ov = __shfl_xor(mv, off);
                const int   oi = __shfl_xor(mi, off);
                if (ov < mv || (ov == mv && oi >= 0 && (mi < 0 || oi < mi))) { mv = ov; mi = oi; }
            }
            if (lx == 0 && mi >= 0) {
                const u64 pk = ((u64)fkey(mv) << 32) | (u32)mi;
                atomicMin(&keys[(size_t)b * SEQ + tg], pk);
            }
        }
    }
}

// ================= argmin_lds: R11-verbatim fallback (small ws) =================
__global__ __launch_bounds__(512, 2)
void argmin_lds_kernel(const float* __restrict__ Q, const float* __restrict__ K,
                       const int* __restrict__ mfp, u64* __restrict__ ws)
{
    if (mfp[0] == 0) return;
    __shared__ u32 KTh[2][128][32];
    __shared__ u32 KTl[2][128][32];
    __shared__ float sx[128][68];

    const int tid  = threadIdx.x;
    const int w    = tid >> 6, wp = w & 3, h = w >> 2;
    const int lane = tid & 63, lx = lane & 15, lg = lane >> 4;

    int j = blockIdx.x;
    const int b = j / 272; j -= b * 272;
    int mg = 0;
    while (true) { const int n = 16 - (mg >> 1); if (j < n) break; j -= n; mg++; }
    const int m0 = mg * 64;
    const int s0 = (m0 & ~127) + 128 * j;

    const float* __restrict__ Qb = Q + (size_t)b * SEQ * DIM;
    const float* __restrict__ Kb = K + (size_t)b * SEQ * DIM;
    const int krow = (tid >> 1) & 127;
    const int ksc  = tid & 1;

    h8 qh[8], ql[8];
    {
        const float* qrowp = Qb + (size_t)(m0 + 16 * wp + lx) * DIM;
        #pragma unroll
        for (int t = 0; t < 8; t++) {
            float bufv[8];
            *(f4*)&bufv[0] = *(const f4*)(qrowp + 256 * h + 32 * t + 8 * lg);
            *(f4*)&bufv[4] = *(const f4*)(qrowp + 256 * h + 32 * t + 8 * lg + 4);
            u4v uh, ul;
            #pragma unroll
            for (int p = 0; p < 4; p++) {
                const HL hl = split2t(bufv[2*p], bufv[2*p+1]);
                uh[p] = hl.hi; ul[p] = hl.lo;
            }
            qh[t] = __builtin_bit_cast(h8, uh);
            ql[t] = __builtin_bit_cast(h8, ul);
        }
    }
    const f4 fz = {0.f, 0.f, 0.f, 0.f};
    f4 sa[8];
    #pragma unroll
    for (int nt = 0; nt < 8; nt++) sa[nt] = fz;

    f4 kreg[8];
    #pragma unroll
    for (int c = 0; c < 8; c++)
        kreg[c] = *(const f4*)(Kb + (size_t)(s0 + krow) * DIM + 256 * h + 32 * ksc + 4 * c);

    #pragma unroll
    for (int i = 0; i < 4; i++) {
        if (i) __syncthreads();
        {
            u32 HH[16], LL[16];
            #pragma unroll
            for (int c = 0; c < 8; c++) {
                const HL e0 = split2t(kreg[c][0], kreg[c][1]);
                const HL e1 = split2t(kreg[c][2], kreg[c][3]);
                HH[2*c] = e0.hi;   LL[2*c] = e0.lo;
                HH[2*c+1] = e1.hi; LL[2*c+1] = e1.lo;
            }
            #pragma unroll
            for (int qd = 0; qd < 4; qd++) {
                const int gp = ((4 * ksc + qd) ^ (krow & 7)) * 4;
                u4v vh = {HH[4*qd], HH[4*qd+1], HH[4*qd+2], HH[4*qd+3]};
                u4v vl = {LL[4*qd], LL[4*qd+1], LL[4*qd+2], LL[4*qd+3]};
                *(u4v*)&KTh[h][krow][gp] = vh;
                *(u4v*)&KTl[h][krow][gp] = vl;
            }
        }
        __syncthreads();
        if (i < 3) {
            #pragma unroll
            for (int c = 0; c < 8; c++)
                kreg[c] = *(const f4*)(Kb + (size_t)(s0 + krow) * DIM
                                       + 256 * h + 64 * (i + 1) + 32 * ksc + 4 * c);
        }
        __builtin_amdgcn_s_setprio(1);
        #pragma unroll
        for (int tl = 0; tl < 2; tl++) {
            const int t = 2 * i + tl;
            #pragma unroll
            for (int nt = 0; nt < 8; nt++) {
                const int s  = 16 * nt + lx;
                const int gp = ((4 * tl + lg) ^ (s & 7)) * 4;
                const h8 kh = __builtin_bit_cast(h8, *(const u4v*)&KTh[h][s][gp]);
                const h8 kl = __builtin_bit_cast(h8, *(const u4v*)&KTl[h][s][gp]);
                sa[nt] = MFMA16(qh[t], kh, sa[nt]);
                sa[nt] = MFMA16(qh[t], kl, sa[nt]);
                sa[nt] = MFMA16(ql[t], kh, sa[nt]);
            }
        }
        __builtin_amdgcn_s_setprio(0);
    }

    if (h == 0) {
        #pragma unroll
        for (int nt = 0; nt < 8; nt++)
            *(f4*)&sx[16 * nt + lx][16 * wp + 4 * lg] = sa[nt];
    }
    __syncthreads();
    if (h == 1) {
        #pragma unroll
        for (int nt = 0; nt < 8; nt++) {
            const f4 part = *(const f4*)&sx[16 * nt + lx][16 * wp + 4 * lg];
            #pragma unroll
            for (int r = 0; r < 4; r++) {
                float s = sa[nt][r] + part[r];
                sa[nt][r] = (s == s) ? s : 0.0f;
            }
        }
        #pragma unroll
        for (int r = 0; r < 4; r++) {
            const int tg = m0 + 16 * wp + 4 * lg + r;
            float mv = INFINITY; int mi = -1;
            #pragma unroll
            for (int nt = 0; nt < 8; nt++) {
                const int sg = s0 + 16 * nt + lx;
                const float v = sa[nt][r];
                if (sg >= tg && v < mv) { mv = v; mi = sg; }
            }
            #pragma unroll
            for (int off = 1; off < 16; off <<= 1) {
                const float ov = __shfl_xor(mv, off);
                const int   oi = __shfl_xor(mi, off);
                if (ov < mv || (ov == mv && oi >= 0 && (mi < 0 || oi < mi))) { mv = ov; mi = oi; }
            }
            if (lx == 0 && mi >= 0) {
                const u64 pk = ((u64)fkey(mv) << 32) | (u32)mi;
                atomicMin(&ws[(size_t)b * SEQ + tg], pk);
            }
        }
    }
}

// ================= gather + worklist (R10-verbatim) =================
__global__ __launch_bounds__(512, 2)
void gather_kernel(const float* __restrict__ V, const u64* __restrict__ keys,
                   u32* __restrict__ cnt, u32* __restrict__ list,
                   float* __restrict__ Out)
{
    const int tid  = threadIdx.x;
    const int w    = tid >> 6;
    const int lane = tid & 63;
    const int b    = blockIdx.x >> 5;
    const int m0   = (blockIdx.x & 31) * 64;

    const float* __restrict__ Vb = V + (size_t)b * SEQ * DIM;
    float* __restrict__ Ob = Out + (size_t)b * SEQ * DIM;

    #pragma unroll
    for (int rr = 0; rr < 8; rr++) {
        const int tg = m0 + 8 * w + rr;
        const u64 pk = keys[(size_t)b * SEQ + tg];
        const u32 key = (u32)(pk >> 32);
        if (key < 0x80000000u) {
            const int ss = (int)(pk & 0xFFFFFFFFu);
            #pragma unroll
            for (int it = 0; it < 2; it++) {
                const int col = 256 * it + 4 * lane;
                *(f4*)(Ob + (size_t)tg * DIM + col) = *(const f4*)(Vb + (size_t)ss * DIM + col);
            }
        } else if (lane == 0) {
            const u32 p = atomicAdd(cnt, 1u);
            list[p] = ((u32)b << 16) | (u32)tg;
        }
    }
}

// ====== fb_part (R11-verbatim) ======
__global__ __launch_bounds__(512, 2)
void fb_part_kernel(const float* __restrict__ Q, const float* __restrict__ K,
                    const float* __restrict__ V, const int* __restrict__ mfp,
                    const u32* __restrict__ cnt, const u32* __restrict__ list,
                    float2* __restrict__ meta, float* __restrict__ partials)
{
    __shared__ float qrow[DIM];
    __shared__ float zpart[4][CHW];
    __shared__ float zs[CHW];
    __shared__ float zp[CHW];
    __shared__ f4    pacc[4][128];
    __shared__ float red2[2];

    const int tid = threadIdx.x;
    const int mf  = mfp[0];
    const float dk = 22.627416997969522f;

    const int n  = (int)cnt[0];
    const int nw = min(n * NCH, CAP);

    for (int wi = blockIdx.x; wi < nw; wi += gridDim.x) {
        const int ridx  = wi >> 4;
        const int chunk = wi & 15;
        const u32 e  = list[ridx];
        const int b  = (int)(e >> 16);
        const int tg = (int)(e & 0xFFFFu);

        const float* __restrict__ Qb = Q + (size_t)b * SEQ * DIM;
        const float* __restrict__ Kb = K + (size_t)b * SEQ * DIM;
        const float* __restrict__ Vb = V + (size_t)b * SEQ * DIM;

        if (tid < 128) *(f4*)&qrow[4 * tid] = *(const f4*)(Qb + (size_t)tg * DIM + 4 * tid);
        __syncthreads();
        {
            const int jj   = tid & 127;
            const int dseg = tid >> 7;
            const int col  = chunk * CHW + jj;
            const float* kr = Kb + (size_t)col * DIM + 128 * dseg;
            float acc = 0.f;
            #pragma unroll 8
            for (int d4 = 0; d4 < 32; d4++) {
                const f4 q = *(const f4*)&qrow[4 * (32 * dseg + d4)];
                const f4 k = *(const f4*)(kr + 4 * d4);
                acc += q[0]*k[0] + q[1]*k[1] + q[2]*k[2] + q[3]*k[3];
            }
            zpart[dseg][jj] = acc;
        }
        __syncthreads();
        if (tid < 128) {
            const int col = chunk * CHW + tid;
            float z = zpart[0][tid] + zpart[1][tid] + zpart[2][tid] + zpart[3][tid];
            const float mult = (mf && col >= tg) ? -1.0e9f : 1.0f;
            zs[tid] = z * mult / dk;
        }
        __syncthreads();
        if (tid < 64) {
            float m = fmaxf(zs[tid], zs[tid + 64]);
            #pragma unroll
            for (int off = 1; off < 64; off <<= 1) m = fmaxf(m, __shfl_xor(m, off));
            if (tid == 0) red2[0] = m;
        }
        __syncthreads();
        const float M = red2[0];
        if (tid < 128) zp[tid] = expf(zs[tid] - M);
        __syncthreads();
        if (tid < 64) {
            float s = zp[tid] + zp[tid + 64];
            #pragma unroll
            for (int off = 1; off < 64; off <<= 1) s += __shfl_xor(s, off);
            if (tid == 0) red2[1] = s;
        }
        {
            const int dq   = tid & 127;
            const int sseg = tid >> 7;
            f4 acc = {0.f, 0.f, 0.f, 0.f};
            const int sb = chunk * CHW + 32 * sseg;
            #pragma unroll 8
            for (int s = 0; s < 32; s++)
                acc += zp[32 * sseg + s] * *(const f4*)(Vb + (size_t)(sb + s) * DIM + 4 * dq);
            pacc[sseg][dq] = acc;
        }
        __syncthreads();
        if (tid < 128) {
            const f4 nc = pacc[0][tid] + pacc[1][tid] + pacc[2][tid] + pacc[3][tid];
            *(f4*)&partials[(size_t)wi * DIM + 4 * tid] = nc;
        }
        if (tid == 0) meta[wi] = make_float2(M, red2[1]);
        __syncthreads();
    }
}

// ====== fb_combine (R11-verbatim) ======
__global__ __launch_bounds__(512, 2)
void fb_combine_kernel(const float* __restrict__ Q, const float* __restrict__ K,
                       const float* __restrict__ V, const int* __restrict__ mfp,
                       const u32* __restrict__ cnt, const u32* __restrict__ list,
                       const float2* __restrict__ meta, const float* __restrict__ partials,
                       float* __restrict__ Out)
{
    __shared__ float qrow[DIM];
    __shared__ float zrow[SEQ];
    __shared__ float red[8];
    __shared__ f4    pacc[4][128];

    const int tid  = threadIdx.x;
    const int w    = tid >> 6;
    const int lane = tid & 63;
    const int mf   = mfp[0];
    const float dk = 22.627416997969522f;

    const int n = (int)cnt[0];
    for (int idx = blockIdx.x; idx < n; idx += gridDim.x) {
        const u32 e  = list[idx];
        const int b  = (int)(e >> 16);
        const int tg = (int)(e & 0xFFFFu);
        float* __restrict__ Ob = Out + (size_t)b * SEQ * DIM;

        if (idx < CAP / NCH) {
            float M = -INFINITY;
            #pragma unroll
            for (int c = 0; c < NCH; c++) M = fmaxf(M, meta[idx * NCH + c].x);
            float L = 0.f, o = 0.f;
            #pragma unroll
            for (int c = 0; c < NCH; c++) {
                const float2 mc = meta[idx * NCH + c];
                const float fct = expf(mc.x - M);
                L += mc.y * fct;
                o += partials[(size_t)(idx * NCH + c) * DIM + tid] * fct;
            }
            Ob[(size_t)tg * DIM + tid] = o / L;
        } else {
            const float* __restrict__ Qb = Q + (size_t)b * SEQ * DIM;
            const float* __restrict__ Kb = K + (size_t)b * SEQ * DIM;
            const float* __restrict__ Vb = V + (size_t)b * SEQ * DIM;
            if (tid < 128) *(f4*)&qrow[4 * tid] = *(const f4*)(Qb + (size_t)tg * DIM + 4 * tid);
            __syncthreads();
            float z4[4];
            #pragma unroll
            for (int c4 = 0; c4 < 4; c4++) {
                const int col = tid + 512 * c4;
                const float* kr = Kb + (size_t)col * DIM;
                float acc = 0.f;
                #pragma unroll 4
                for (int d4 = 0; d4 < 128; d4++) {
                    const f4 q = *(const f4*)&qrow[4 * d4];
                    const f4 k = *(const f4*)(kr + 4 * d4);
                    acc += q[0]*k[0] + q[1]*k[1] + q[2]*k[2] + q[3]*k[3];
                }
                const float mult = (mf && col >= tg) ? -1.0e9f : 1.0f;
                z4[c4] = acc * mult / dk;
            }
            float lm = fmaxf(fmaxf(z4[0], z4[1]), fmaxf(z4[2], z4[3]));
            #pragma unroll
            for (int off = 1; off < 64; off <<= 1) lm = fmaxf(lm, __shfl_xor(lm, off));
            if (lane == 0) red[w] = lm;
            __syncthreads();
            float M = red[0];
            #pragma unroll
            for (int i = 1; i < 8; i++) M = fmaxf(M, red[i]);
            float ls = 0.f;
            #pragma unroll
            for (int c4 = 0; c4 < 4; c4++) {
                const float p = expf(z4[c4] - M);
                zrow[tid + 512 * c4] = p;
                ls += p;
            }
            #pragma unroll
            for (int off = 1; off < 64; off <<= 1) ls += __shfl_xor(ls, off);
            __syncthreads();
            if (lane == 0) red[w] = ls;
            __syncthreads();
            float L = 0.f;
            #pragma unroll
            for (int i = 0; i < 8; i++) L += red[i];
            const int dq = tid & 127;
            const int sq = tid >> 7;
            f4 acc = {0.f, 0.f, 0.f, 0.f};
            const int sbeg = 512 * sq;
            #pragma unroll 8
            for (int s = 0; s < 512; s++)
                acc += zrow[sbeg + s] * *(const f4*)(Vb + (size_t)(sbeg + s) * DIM + 4 * dq);
            pacc[sq][dq] = acc;
            __syncthreads();
            if (tid < 128) {
                f4 r = pacc[0][tid] + pacc[1][tid] + pacc[2][tid] + pacc[3][tid];
                const float il = 1.0f / L;
                r[0] *= il; r[1] *= il; r[2] *= il; r[3] *= il;
                *(f4*)(Ob + (size_t)tg * DIM + 4 * tid) = r;
            }
            __syncthreads();
        }
    }
}

extern "C" void kernel_launch(void* const* d_in, const int* in_sizes, int n_in,
                              void* d_out, int out_size, void* d_ws, size_t ws_size,
                              hipStream_t stream) {
    const float* Q  = (const float*)d_in[0];
    const float* K  = (const float*)d_in[1];
    const float* V  = (const float*)d_in[2];
    const int*   mf = (const int*)d_in[3];
    float* O = (float*)d_out;

    char* wsb = (char*)d_ws;
    u64*    keys     = (u64*)wsb;                                   // 128 KB
    u32*    cnt      = (u32*)(wsb + 131072);
    u32*    list     = (u32*)(wsb + 131072 + 256);                  // 64 KB
    float2* meta     = (float2*)(wsb + 131072 + 256 + 65536);       // 4 KB
    float*  partials = (float*)(wsb + 131072 + 256 + 65536 + 8192); // 1 MB

    const size_t SPLIT_OFF = 1310720;                 // 1.25 MB, 16B-aligned
    const size_t ARR = (size_t)BATCH * SEQ * 256 * 4; // 16 MB per array
    u32* Qh = (u32*)(wsb + SPLIT_OFF);
    u32* Ql = (u32*)(wsb + SPLIT_OFF + ARR);
    u32* Kh = (u32*)(wsb + SPLIT_OFF + 2 * ARR);
    u32* Kl = (u32*)(wsb + SPLIT_OFF + 3 * ARR);
    const bool big_ws = ws_size >= SPLIT_OFF + 4 * ARR;

    hipMemsetAsync(keys, 0xFF, (size_t)BATCH * SEQ * sizeof(u64), stream);
    hipMemsetAsync(cnt, 0, sizeof(u32), stream);

    if (big_ws) {
        prep_q2_kernel<<<dim3(1024), dim3(256), 0, stream>>>(Q, Qh, Ql);
        prep_k2_kernel<<<dim3(2048), dim3(256), 0, stream>>>(K, Kh, Kl);
        argmin3_kernel<<<dim3(576), dim3(256), 0, stream>>>(Qh, Ql, Kh, Kl, mf, keys);
    } else {
        argmin_lds_kernel<<<dim3(BATCH * 272), dim3(512), 0, stream>>>(Q, K, mf, keys);
    }
    gather_kernel<<<dim3(BATCH * (SEQ / 64)), dim3(512), 0, stream>>>(V, keys, cnt, list, O);
    fb_part_kernel<<<dim3(512), dim3(512), 0, stream>>>(Q, K, V, mf, cnt, list, meta, partials);
    fb_combine_kernel<<<dim3(128), dim3(512), 0, stream>>>(Q, K, V, mf, cnt, list, meta, partials, O);
}

// Round 18
// 144.567 us; speedup vs baseline: 1.9886x; 1.1309x over previous
//
#include <hip/hip_runtime.h>
#include <math.h>

#define BATCH 8
#define SEQ   2048
#define DIM   512
#define NCH   16
#define CHW   128
#define CAP   512

typedef unsigned int u32;
typedef unsigned long long u64;
typedef _Float16 h2  __attribute__((ext_vector_type(2)));
typedef _Float16 h8  __attribute__((ext_vector_type(8)));
typedef float    f4  __attribute__((ext_vector_type(4)));
typedef u32      u4v __attribute__((ext_vector_type(4)));

#define MFMA16(a,b,c) __builtin_amdgcn_mfma_f32_16x16x32_f16((a),(b),(c),0,0,0)

struct HL { u32 hi, lo; };
__device__ __forceinline__ HL split2t(float a, float b) {
    _Float16 ha = (_Float16)a, hb = (_Float16)b;
    h2 th; th[0] = ha; th[1] = hb;
    h2 tl; tl[0] = (_Float16)(a - (float)ha); tl[1] = (_Float16)(b - (float)hb);
    HL r; r.hi = __builtin_bit_cast(u32, th); r.lo = __builtin_bit_cast(u32, tl);
    return r;
}
__device__ __forceinline__ u32 fkey(float f) {
    u32 v = __builtin_bit_cast(u32, f);
    return (v & 0x80000000u) ? ~v : (v | 0x80000000u);
}

// ==== fused prep: blocks 0..1023 do Q, 1024..3071 do K (overlapped streams) ====
// Q layout [b][g16][t][lane][4]; K layout [b][st][t][nt][lane][4] (R17-verbatim).
__global__ __launch_bounds__(256, 4)
void prep_kernel(const float* __restrict__ Q, const float* __restrict__ K,
                 u32* __restrict__ Qh, u32* __restrict__ Ql,
                 u32* __restrict__ Kh, u32* __restrict__ Kl)
{
    const int lane = threadIdx.x & 63;
    const int lx   = lane & 15, lg = lane >> 4;
    if (blockIdx.x < 1024) {
        const int b    = blockIdx.x >> 7;
        const int g16  = blockIdx.x & 127;
        const int tq   = threadIdx.x >> 6;
        const float* src0 = Q + ((size_t)(b * SEQ + g16 * 16 + lx)) * DIM + 8 * lg;
        #pragma unroll
        for (int p = 0; p < 4; p++) {
            const int t = p * 4 + tq;
            const float* s = src0 + 32 * t;
            const f4 r0 = *(const f4*)(s);
            const f4 r1 = *(const f4*)(s + 4);
            const HL p0 = split2t(r0[0], r0[1]);
            const HL p1 = split2t(r0[2], r0[3]);
            const HL p2 = split2t(r1[0], r1[1]);
            const HL p3 = split2t(r1[2], r1[3]);
            u4v vh = {p0.hi, p1.hi, p2.hi, p3.hi};
            u4v vl = {p0.lo, p1.lo, p2.lo, p3.lo};
            const size_t off = (((size_t)(b * 128 + g16) * 16 + t) * 256) + (size_t)lane * 4;
            *(u4v*)(Qh + off) = vh;
            *(u4v*)(Ql + off) = vl;
        }
    } else {
        const int blk  = blockIdx.x - 1024;
        const int b    = blk >> 8;
        const int st   = (blk >> 4) & 15;
        const int t    = blk & 15;
        const int nq   = threadIdx.x >> 6;
        #pragma unroll
        for (int p = 0; p < 2; p++) {
            const int nt = p * 4 + nq;
            const float* s = K + ((size_t)(b * SEQ + 128 * st + 16 * nt + lx)) * DIM + 32 * t + 8 * lg;
            const f4 r0 = *(const f4*)(s);
            const f4 r1 = *(const f4*)(s + 4);
            const HL p0 = split2t(r0[0], r0[1]);
            const HL p1 = split2t(r0[2], r0[3]);
            const HL p2 = split2t(r1[0], r1[1]);
            const HL p3 = split2t(r1[2], r1[3]);
            u4v vh = {p0.hi, p1.hi, p2.hi, p3.hi};
            u4v vl = {p0.lo, p1.lo, p2.lo, p3.lo};
            const size_t off = ((((size_t)(b * 16 + st) * 16 + t) * 8 + nt) * 256) + (size_t)lane * 4;
            *(u4v*)(Kh + off) = vh;
            *(u4v*)(Kl + off) = vl;
        }
    }
}

// ===== argmin4: block = (128-row band, s-tile); wave = 32 rows; sa[2][8]=64 VGPR =====
// 1088 blocks (4.25/CU), launch_bounds(256,3) leaves ~100 regs for load pipelining.
// Maps (R5-R17 validated): A row=lane&15, slot e<->k=8lg+e; B col=lane&15 same;
// C/D row=4lg+reg, col=lane&15.
__global__ __launch_bounds__(256, 3)
void argmin4_kernel(const u32* __restrict__ Qh, const u32* __restrict__ Ql,
                    const u32* __restrict__ Kh, const u32* __restrict__ Kl,
                    const int* __restrict__ mfp, u64* __restrict__ keys)
{
    if (mfp[0] == 0) return;

    const int tid  = threadIdx.x;
    const int b    = blockIdx.x & 7;        // XCD-affine batch (136 jobs/batch)
    int rem        = blockIdx.x >> 3;       // 0..135
    const int w    = tid >> 6;
    const int lane = tid & 63, lx = lane & 15, lg = lane >> 4;

    // decode: 128-row band g (0..15) has 16-g tiles
    int g = 0;
    while (rem >= 16 - g) { rem -= 16 - g; g++; }
    const int st   = g + rem;               // shared s-tile for all 4 waves
    const int s0   = 128 * st;
    const int g16b = 8 * g + 2 * w;         // wave's first 16-row group
    const int m0   = 128 * g + 32 * w;      // wave's first row

    const f4 fz = {0.f, 0.f, 0.f, 0.f};
    f4 sa[2][8];
    #pragma unroll
    for (int rg = 0; rg < 2; rg++)
        #pragma unroll
        for (int nt = 0; nt < 8; nt++) sa[rg][nt] = fz;

    const size_t qoff = ((size_t)(b * 128 + g16b) * 16) * 256 + (size_t)lane * 4;
    const size_t koff = ((size_t)(b * 16 + st) * 128) * 256 + (size_t)lane * 4;

    #pragma unroll
    for (int t = 0; t < 16; t++) {
        h8 ah[2], al[2];
        #pragma unroll
        for (int rg = 0; rg < 2; rg++) {
            ah[rg] = __builtin_bit_cast(h8, *(const u4v*)(Qh + qoff + (size_t)(rg * 16 + t) * 256));
            al[rg] = __builtin_bit_cast(h8, *(const u4v*)(Ql + qoff + (size_t)(rg * 16 + t) * 256));
        }
        #pragma unroll
        for (int nt = 0; nt < 8; nt++) {
            const h8 kh = __builtin_bit_cast(h8, *(const u4v*)(Kh + koff + (size_t)(t * 8 + nt) * 256));
            const h8 kl = __builtin_bit_cast(h8, *(const u4v*)(Kl + koff + (size_t)(t * 8 + nt) * 256));
            #pragma unroll
            for (int rg = 0; rg < 2; rg++) {
                sa[rg][nt] = MFMA16(ah[rg], kh, sa[rg][nt]);
                sa[rg][nt] = MFMA16(ah[rg], kl, sa[rg][nt]);
                sa[rg][nt] = MFMA16(al[rg], kh, sa[rg][nt]);
            }
        }
    }

    // ---- NaN scrub (insurance) + masked argmin + atomicMin (per 16-row grp) ----
    #pragma unroll
    for (int rg = 0; rg < 2; rg++) {
        #pragma unroll
        for (int nt = 0; nt < 8; nt++)
            #pragma unroll
            for (int r = 0; r < 4; r++) {
                float s = sa[rg][nt][r];
                sa[rg][nt][r] = (s == s) ? s : 0.0f;
            }
        #pragma unroll
        for (int r = 0; r < 4; r++) {
            const int tg = m0 + 16 * rg + 4 * lg + r;
            float mv = INFINITY; int mi = -1;
            #pragma unroll
            for (int nt = 0; nt < 8; nt++) {
                const int sg = s0 + 16 * nt + lx;
                const float v = sa[rg][nt][r];
                if (sg >= tg && v < mv) { mv = v; mi = sg; }
            }
            #pragma unroll
            for (int off = 1; off < 16; off <<= 1) {
                const float ov = __shfl_xor(mv, off);
                const int   oi = __shfl_xor(mi, off);
                if (ov < mv || (ov == mv && oi >= 0 && (mi < 0 || oi < mi))) { mv = ov; mi = oi; }
            }
            if (lx == 0 && mi >= 0) {
                const u64 pk = ((u64)fkey(mv) << 32) | (u32)mi;
                atomicMin(&keys[(size_t)b * SEQ + tg], pk);
            }
        }
    }
}

// ================= argmin_lds: R11-verbatim fallback (small ws) =================
__global__ __launch_bounds__(512, 2)
void argmin_lds_kernel(const float* __restrict__ Q, const float* __restrict__ K,
                       const int* __restrict__ mfp, u64* __restrict__ ws)
{
    if (mfp[0] == 0) return;
    __shared__ u32 KTh[2][128][32];
    __shared__ u32 KTl[2][128][32];
    __shared__ float sx[128][68];

    const int tid  = threadIdx.x;
    const int w    = tid >> 6, wp = w & 3, h = w >> 2;
    const int lane = tid & 63, lx = lane & 15, lg = lane >> 4;

    int j = blockIdx.x;
    const int b = j / 272; j -= b * 272;
    int mg = 0;
    while (true) { const int n = 16 - (mg >> 1); if (j < n) break; j -= n; mg++; }
    const int m0 = mg * 64;
    const int s0 = (m0 & ~127) + 128 * j;

    const float* __restrict__ Qb = Q + (size_t)b * SEQ * DIM;
    const float* __restrict__ Kb = K + (size_t)b * SEQ * DIM;
    const int krow = (tid >> 1) & 127;
    const int ksc  = tid & 1;

    h8 qh[8], ql[8];
    {
        const float* qrowp = Qb + (size_t)(m0 + 16 * wp + lx) * DIM;
        #pragma unroll
        for (int t = 0; t < 8; t++) {
            float bufv[8];
            *(f4*)&bufv[0] = *(const f4*)(qrowp + 256 * h + 32 * t + 8 * lg);
            *(f4*)&bufv[4] = *(const f4*)(qrowp + 256 * h + 32 * t + 8 * lg + 4);
            u4v uh, ul;
            #pragma unroll
            for (int p = 0; p < 4; p++) {
                const HL hl = split2t(bufv[2*p], bufv[2*p+1]);
                uh[p] = hl.hi; ul[p] = hl.lo;
            }
            qh[t] = __builtin_bit_cast(h8, uh);
            ql[t] = __builtin_bit_cast(h8, ul);
        }
    }
    const f4 fz = {0.f, 0.f, 0.f, 0.f};
    f4 sa[8];
    #pragma unroll
    for (int nt = 0; nt < 8; nt++) sa[nt] = fz;

    f4 kreg[8];
    #pragma unroll
    for (int c = 0; c < 8; c++)
        kreg[c] = *(const f4*)(Kb + (size_t)(s0 + krow) * DIM + 256 * h + 32 * ksc + 4 * c);

    #pragma unroll
    for (int i = 0; i < 4; i++) {
        if (i) __syncthreads();
        {
            u32 HH[16], LL[16];
            #pragma unroll
            for (int c = 0; c < 8; c++) {
                const HL e0 = split2t(kreg[c][0], kreg[c][1]);
                const HL e1 = split2t(kreg[c][2], kreg[c][3]);
                HH[2*c] = e0.hi;   LL[2*c] = e0.lo;
                HH[2*c+1] = e1.hi; LL[2*c+1] = e1.lo;
            }
            #pragma unroll
            for (int qd = 0; qd < 4; qd++) {
                const int gp = ((4 * ksc + qd) ^ (krow & 7)) * 4;
                u4v vh = {HH[4*qd], HH[4*qd+1], HH[4*qd+2], HH[4*qd+3]};
                u4v vl = {LL[4*qd], LL[4*qd+1], LL[4*qd+2], LL[4*qd+3]};
                *(u4v*)&KTh[h][krow][gp] = vh;
                *(u4v*)&KTl[h][krow][gp] = vl;
            }
        }
        __syncthreads();
        if (i < 3) {
            #pragma unroll
            for (int c = 0; c < 8; c++)
                kreg[c] = *(const f4*)(Kb + (size_t)(s0 + krow) * DIM
                                       + 256 * h + 64 * (i + 1) + 32 * ksc + 4 * c);
        }
        __builtin_amdgcn_s_setprio(1);
        #pragma unroll
        for (int tl = 0; tl < 2; tl++) {
            const int t = 2 * i + tl;
            #pragma unroll
            for (int nt = 0; nt < 8; nt++) {
                const int s  = 16 * nt + lx;
                const int gp = ((4 * tl + lg) ^ (s & 7)) * 4;
                const h8 kh = __builtin_bit_cast(h8, *(const u4v*)&KTh[h][s][gp]);
                const h8 kl = __builtin_bit_cast(h8, *(const u4v*)&KTl[h][s][gp]);
                sa[nt] = MFMA16(qh[t], kh, sa[nt]);
                sa[nt] = MFMA16(qh[t], kl, sa[nt]);
                sa[nt] = MFMA16(ql[t], kh, sa[nt]);
            }
        }
        __builtin_amdgcn_s_setprio(0);
    }

    if (h == 0) {
        #pragma unroll
        for (int nt = 0; nt < 8; nt++)
            *(f4*)&sx[16 * nt + lx][16 * wp + 4 * lg] = sa[nt];
    }
    __syncthreads();
    if (h == 1) {
        #pragma unroll
        for (int nt = 0; nt < 8; nt++) {
            const f4 part = *(const f4*)&sx[16 * nt + lx][16 * wp + 4 * lg];
            #pragma unroll
            for (int r = 0; r < 4; r++) {
                float s = sa[nt][r] + part[r];
                sa[nt][r] = (s == s) ? s : 0.0f;
            }
        }
        #pragma unroll
        for (int r = 0; r < 4; r++) {
            const int tg = m0 + 16 * wp + 4 * lg + r;
            float mv = INFINITY; int mi = -1;
            #pragma unroll
            for (int nt = 0; nt < 8; nt++) {
                const int sg = s0 + 16 * nt + lx;
                const float v = sa[nt][r];
                if (sg >= tg && v < mv) { mv = v; mi = sg; }
            }
            #pragma unroll
            for (int off = 1; off < 16; off <<= 1) {
                const float ov = __shfl_xor(mv, off);
                const int   oi = __shfl_xor(mi, off);
                if (ov < mv || (ov == mv && oi >= 0 && (mi < 0 || oi < mi))) { mv = ov; mi = oi; }
            }
            if (lx == 0 && mi >= 0) {
                const u64 pk = ((u64)fkey(mv) << 32) | (u32)mi;
                atomicMin(&ws[(size_t)b * SEQ + tg], pk);
            }
        }
    }
}

// ================= gather + worklist (R10-verbatim) =================
__global__ __launch_bounds__(512, 2)
void gather_kernel(const float* __restrict__ V, const u64* __restrict__ keys,
                   u32* __restrict__ cnt, u32* __restrict__ list,
                   float* __restrict__ Out)
{
    const int tid  = threadIdx.x;
    const int w    = tid >> 6;
    const int lane = tid & 63;
    const int b    = blockIdx.x >> 5;
    const int m0   = (blockIdx.x & 31) * 64;

    const float* __restrict__ Vb = V + (size_t)b * SEQ * DIM;
    float* __restrict__ Ob = Out + (size_t)b * SEQ * DIM;

    #pragma unroll
    for (int rr = 0; rr < 8; rr++) {
        const int tg = m0 + 8 * w + rr;
        const u64 pk = keys[(size_t)b * SEQ + tg];
        const u32 key = (u32)(pk >> 32);
        if (key < 0x80000000u) {
            const int ss = (int)(pk & 0xFFFFFFFFu);
            #pragma unroll
            for (int it = 0; it < 2; it++) {
                const int col = 256 * it + 4 * lane;
                *(f4*)(Ob + (size_t)tg * DIM + col) = *(const f4*)(Vb + (size_t)ss * DIM + col);
            }
        } else if (lane == 0) {
            const u32 p = atomicAdd(cnt, 1u);
            list[p] = ((u32)b << 16) | (u32)tg;
        }
    }
}

// ====== fb_part (R11-verbatim) ======
__global__ __launch_bounds__(512, 2)
void fb_part_kernel(const float* __restrict__ Q, const float* __restrict__ K,
                    const float* __restrict__ V, const int* __restrict__ mfp,
                    const u32* __restrict__ cnt, const u32* __restrict__ list,
                    float2* __restrict__ meta, float* __restrict__ partials)
{
    __shared__ float qrow[DIM];
    __shared__ float zpart[4][CHW];
    __shared__ float zs[CHW];
    __shared__ float zp[CHW];
    __shared__ f4    pacc[4][128];
    __shared__ float red2[2];

    const int tid = threadIdx.x;
    const int mf  = mfp[0];
    const float dk = 22.627416997969522f;

    const int n  = (int)cnt[0];
    const int nw = min(n * NCH, CAP);

    for (int wi = blockIdx.x; wi < nw; wi += gridDim.x) {
        const int ridx  = wi >> 4;
        const int chunk = wi & 15;
        const u32 e  = list[ridx];
        const int b  = (int)(e >> 16);
        const int tg = (int)(e & 0xFFFFu);

        const float* __restrict__ Qb = Q + (size_t)b * SEQ * DIM;
        const float* __restrict__ Kb = K + (size_t)b * SEQ * DIM;
        const float* __restrict__ Vb = V + (size_t)b * SEQ * DIM;

        if (tid < 128) *(f4*)&qrow[4 * tid] = *(const f4*)(Qb + (size_t)tg * DIM + 4 * tid);
        __syncthreads();
        {
            const int jj   = tid & 127;
            const int dseg = tid >> 7;
            const int col  = chunk * CHW + jj;
            const float* kr = Kb + (size_t)col * DIM + 128 * dseg;
            float acc = 0.f;
            #pragma unroll 8
            for (int d4 = 0; d4 < 32; d4++) {
                const f4 q = *(const f4*)&qrow[4 * (32 * dseg + d4)];
                const f4 k = *(const f4*)(kr + 4 * d4);
                acc += q[0]*k[0] + q[1]*k[1] + q[2]*k[2] + q[3]*k[3];
            }
            zpart[dseg][jj] = acc;
        }
        __syncthreads();
        if (tid < 128) {
            const int col = chunk * CHW + tid;
            float z = zpart[0][tid] + zpart[1][tid] + zpart[2][tid] + zpart[3][tid];
            const float mult = (mf && col >= tg) ? -1.0e9f : 1.0f;
            zs[tid] = z * mult / dk;
        }
        __syncthreads();
        if (tid < 64) {
            float m = fmaxf(zs[tid], zs[tid + 64]);
            #pragma unroll
            for (int off = 1; off < 64; off <<= 1) m = fmaxf(m, __shfl_xor(m, off));
            if (tid == 0) red2[0] = m;
        }
        __syncthreads();
        const float M = red2[0];
        if (tid < 128) zp[tid] = expf(zs[tid] - M);
        __syncthreads();
        if (tid < 64) {
            float s = zp[tid] + zp[tid + 64];
            #pragma unroll
            for (int off = 1; off < 64; off <<= 1) s += __shfl_xor(s, off);
            if (tid == 0) red2[1] = s;
        }
        {
            const int dq   = tid & 127;
            const int sseg = tid >> 7;
            f4 acc = {0.f, 0.f, 0.f, 0.f};
            const int sb = chunk * CHW + 32 * sseg;
            #pragma unroll 8
            for (int s = 0; s < 32; s++)
                acc += zp[32 * sseg + s] * *(const f4*)(Vb + (size_t)(sb + s) * DIM + 4 * dq);
            pacc[sseg][dq] = acc;
        }
        __syncthreads();
        if (tid < 128) {
            const f4 nc = pacc[0][tid] + pacc[1][tid] + pacc[2][tid] + pacc[3][tid];
            *(f4*)&partials[(size_t)wi * DIM + 4 * tid] = nc;
        }
        if (tid == 0) meta[wi] = make_float2(M, red2[1]);
        __syncthreads();
    }
}

// ====== fb_combine (R11-verbatim) ======
__global__ __launch_bounds__(512, 2)
void fb_combine_kernel(const float* __restrict__ Q, const float* __restrict__ K,
                       const float* __restrict__ V, const int* __restrict__ mfp,
                       const u32* __restrict__ cnt, const u32* __restrict__ list,
                       const float2* __restrict__ meta, const float* __restrict__ partials,
                       float* __restrict__ Out)
{
    __shared__ float qrow[DIM];
    __shared__ float zrow[SEQ];
    __shared__ float red[8];
    __shared__ f4    pacc[4][128];

    const int tid  = threadIdx.x;
    const int w    = tid >> 6;
    const int lane = tid & 63;
    const int mf   = mfp[0];
    const float dk = 22.627416997969522f;

    const int n = (int)cnt[0];
    for (int idx = blockIdx.x; idx < n; idx += gridDim.x) {
        const u32 e  = list[idx];
        const int b  = (int)(e >> 16);
        const int tg = (int)(e & 0xFFFFu);
        float* __restrict__ Ob = Out + (size_t)b * SEQ * DIM;

        if (idx < CAP / NCH) {
            float M = -INFINITY;
            #pragma unroll
            for (int c = 0; c < NCH; c++) M = fmaxf(M, meta[idx * NCH + c].x);
            float L = 0.f, o = 0.f;
            #pragma unroll
            for (int c = 0; c < NCH; c++) {
                const float2 mc = meta[idx * NCH + c];
                const float fct = expf(mc.x - M);
                L += mc.y * fct;
                o += partials[(size_t)(idx * NCH + c) * DIM + tid] * fct;
            }
            Ob[(size_t)tg * DIM + tid] = o / L;
        } else {
            const float* __restrict__ Qb = Q + (size_t)b * SEQ * DIM;
            const float* __restrict__ Kb = K + (size_t)b * SEQ * DIM;
            const float* __restrict__ Vb = V + (size_t)b * SEQ * DIM;
            if (tid < 128) *(f4*)&qrow[4 * tid] = *(const f4*)(Qb + (size_t)tg * DIM + 4 * tid);
            __syncthreads();
            float z4[4];
            #pragma unroll
            for (int c4 = 0; c4 < 4; c4++) {
                const int col = tid + 512 * c4;
                const float* kr = Kb + (size_t)col * DIM;
                float acc = 0.f;
                #pragma unroll 4
                for (int d4 = 0; d4 < 128; d4++) {
                    const f4 q = *(const f4*)&qrow[4 * d4];
                    const f4 k = *(const f4*)(kr + 4 * d4);
                    acc += q[0]*k[0] + q[1]*k[1] + q[2]*k[2] + q[3]*k[3];
                }
                const float mult = (mf && col >= tg) ? -1.0e9f : 1.0f;
                z4[c4] = acc * mult / dk;
            }
            float lm = fmaxf(fmaxf(z4[0], z4[1]), fmaxf(z4[2], z4[3]));
            #pragma unroll
            for (int off = 1; off < 64; off <<= 1) lm = fmaxf(lm, __shfl_xor(lm, off));
            if (lane == 0) red[w] = lm;
            __syncthreads();
            float M = red[0];
            #pragma unroll
            for (int i = 1; i < 8; i++) M = fmaxf(M, red[i]);
            float ls = 0.f;
            #pragma unroll
            for (int c4 = 0; c4 < 4; c4++) {
                const float p = expf(z4[c4] - M);
                zrow[tid + 512 * c4] = p;
                ls += p;
            }
            #pragma unroll
            for (int off = 1; off < 64; off <<= 1) ls += __shfl_xor(ls, off);
            __syncthreads();
            if (lane == 0) red[w] = ls;
            __syncthreads();
            float L = 0.f;
            #pragma unroll
            for (int i = 0; i < 8; i++) L += red[i];
            const int dq = tid & 127;
            const int sq = tid >> 7;
            f4 acc = {0.f, 0.f, 0.f, 0.f};
            const int sbeg = 512 * sq;
            #pragma unroll 8
            for (int s = 0; s < 512; s++)
                acc += zrow[sbeg + s] * *(const f4*)(Vb + (size_t)(sbeg + s) * DIM + 4 * dq);
            pacc[sq][dq] = acc;
            __syncthreads();
            if (tid < 128) {
                f4 r = pacc[0][tid] + pacc[1][tid] + pacc[2][tid] + pacc[3][tid];
                const float il = 1.0f / L;
                r[0] *= il; r[1] *= il; r[2] *= il; r[3] *= il;
                *(f4*)(Ob + (size_t)tg * DIM + 4 * tid) = r;
            }
            __syncthreads();
        }
    }
}

extern "C" void kernel_launch(void* const* d_in, const int* in_sizes, int n_in,
                              void* d_out, int out_size, void* d_ws, size_t ws_size,
                              hipStream_t stream) {
    const float* Q  = (const float*)d_in[0];
    const float* K  = (const float*)d_in[1];
    const float* V  = (const float*)d_in[2];
    const int*   mf = (const int*)d_in[3];
    float* O = (float*)d_out;

    char* wsb = (char*)d_ws;
    u64*    keys     = (u64*)wsb;                                   // 128 KB
    u32*    cnt      = (u32*)(wsb + 131072);
    u32*    list     = (u32*)(wsb + 131072 + 256);                  // 64 KB
    float2* meta     = (float2*)(wsb + 131072 + 256 + 65536);       // 4 KB
    float*  partials = (float*)(wsb + 131072 + 256 + 65536 + 8192); // 1 MB

    const size_t SPLIT_OFF = 1310720;                 // 1.25 MB, 16B-aligned
    const size_t ARR = (size_t)BATCH * SEQ * 256 * 4; // 16 MB per array
    u32* Qh = (u32*)(wsb + SPLIT_OFF);
    u32* Ql = (u32*)(wsb + SPLIT_OFF + ARR);
    u32* Kh = (u32*)(wsb + SPLIT_OFF + 2 * ARR);
    u32* Kl = (u32*)(wsb + SPLIT_OFF + 3 * ARR);
    const bool big_ws = ws_size >= SPLIT_OFF + 4 * ARR;

    hipMemsetAsync(keys, 0xFF, (size_t)BATCH * SEQ * sizeof(u64), stream);
    hipMemsetAsync(cnt, 0, sizeof(u32), stream);

    if (big_ws) {
        prep_kernel<<<dim3(3072), dim3(256), 0, stream>>>(Q, K, Qh, Ql, Kh, Kl);
        argmin4_kernel<<<dim3(1088), dim3(256), 0, stream>>>(Qh, Ql, Kh, Kl, mf, keys);
    } else {
        argmin_lds_kernel<<<dim3(BATCH * 272), dim3(512), 0, stream>>>(Q, K, mf, keys);
    }
    gather_kernel<<<dim3(BATCH * (SEQ / 64)), dim3(512), 0, stream>>>(V, keys, cnt, list, O);
    fb_part_kernel<<<dim3(512), dim3(512), 0, stream>>>(Q, K, V, mf, cnt, list, meta, partials);
    fb_combine_kernel<<<dim3(128), dim3(512), 0, stream>>>(Q, K, V, mf, cnt, list, meta, partials, O);
}

// Round 19
// 129.381 us; speedup vs baseline: 2.2220x; 1.1174x over previous
//
#include <hip/hip_runtime.h>
#include <math.h>

#define BATCH 8
#define SEQ   2048
#define DIM   512
#define NCH   16
#define CHW   128
#define CAP   512

typedef unsigned int u32;
typedef unsigned long long u64;
typedef _Float16 h2  __attribute__((ext_vector_type(2)));
typedef _Float16 h8  __attribute__((ext_vector_type(8)));
typedef float    f4  __attribute__((ext_vector_type(4)));
typedef u32      u4v __attribute__((ext_vector_type(4)));

#define MFMA16(a,b,c) __builtin_amdgcn_mfma_f32_16x16x32_f16((a),(b),(c),0,0,0)

struct HL { u32 hi, lo; };
__device__ __forceinline__ HL split2t(float a, float b) {
    _Float16 ha = (_Float16)a, hb = (_Float16)b;
    h2 th; th[0] = ha; th[1] = hb;
    h2 tl; tl[0] = (_Float16)(a - (float)ha); tl[1] = (_Float16)(b - (float)hb);
    HL r; r.hi = __builtin_bit_cast(u32, th); r.lo = __builtin_bit_cast(u32, tl);
    return r;
}
__device__ __forceinline__ u32 fkey(float f) {
    u32 v = __builtin_bit_cast(u32, f);
    return (v & 0x80000000u) ? ~v : (v | 0x80000000u);
}

// ==== fused prep: blocks 0..1023 do Q, 1024..3071 do K (R18-verbatim) ====
__global__ __launch_bounds__(256, 4)
void prep_kernel(const float* __restrict__ Q, const float* __restrict__ K,
                 u32* __restrict__ Qh, u32* __restrict__ Ql,
                 u32* __restrict__ Kh, u32* __restrict__ Kl)
{
    const int lane = threadIdx.x & 63;
    const int lx   = lane & 15, lg = lane >> 4;
    if (blockIdx.x < 1024) {
        const int b    = blockIdx.x >> 7;
        const int g16  = blockIdx.x & 127;
        const int tq   = threadIdx.x >> 6;
        const float* src0 = Q + ((size_t)(b * SEQ + g16 * 16 + lx)) * DIM + 8 * lg;
        #pragma unroll
        for (int p = 0; p < 4; p++) {
            const int t = p * 4 + tq;
            const float* s = src0 + 32 * t;
            const f4 r0 = *(const f4*)(s);
            const f4 r1 = *(const f4*)(s + 4);
            const HL p0 = split2t(r0[0], r0[1]);
            const HL p1 = split2t(r0[2], r0[3]);
            const HL p2 = split2t(r1[0], r1[1]);
            const HL p3 = split2t(r1[2], r1[3]);
            u4v vh = {p0.hi, p1.hi, p2.hi, p3.hi};
            u4v vl = {p0.lo, p1.lo, p2.lo, p3.lo};
            const size_t off = (((size_t)(b * 128 + g16) * 16 + t) * 256) + (size_t)lane * 4;
            *(u4v*)(Qh + off) = vh;
            *(u4v*)(Ql + off) = vl;
        }
    } else {
        const int blk  = blockIdx.x - 1024;
        const int b    = blk >> 8;
        const int st   = (blk >> 4) & 15;
        const int t    = blk & 15;
        const int nq   = threadIdx.x >> 6;
        #pragma unroll
        for (int p = 0; p < 2; p++) {
            const int nt = p * 4 + nq;
            const float* s = K + ((size_t)(b * SEQ + 128 * st + 16 * nt + lx)) * DIM + 32 * t + 8 * lg;
            const f4 r0 = *(const f4*)(s);
            const f4 r1 = *(const f4*)(s + 4);
            const HL p0 = split2t(r0[0], r0[1]);
            const HL p1 = split2t(r0[2], r0[3]);
            const HL p2 = split2t(r1[0], r1[1]);
            const HL p3 = split2t(r1[2], r1[3]);
            u4v vh = {p0.hi, p1.hi, p2.hi, p3.hi};
            u4v vl = {p0.lo, p1.lo, p2.lo, p3.lo};
            const size_t off = ((((size_t)(b * 16 + st) * 16 + t) * 8 + nt) * 256) + (size_t)lane * 4;
            *(u4v*)(Kh + off) = vh;
            *(u4v*)(Kl + off) = vl;
        }
    }
}

// ===== argmin4: R18 structure; launch_bounds(256,2) -> ~128-reg budget so the
// scheduler can hoist next-step loads under MFMAs; setprio(1) around MFMA bursts
// (barrier-free independent waves = role-diverse regime where T5 pays).
// Maps (R5-R18 validated): A row=lane&15, slot e<->k=8lg+e; B col=lane&15 same;
// C/D row=4lg+reg, col=lane&15.
__global__ __launch_bounds__(256, 2)
void argmin4_kernel(const u32* __restrict__ Qh, const u32* __restrict__ Ql,
                    const u32* __restrict__ Kh, const u32* __restrict__ Kl,
                    const int* __restrict__ mfp, u64* __restrict__ keys)
{
    if (mfp[0] == 0) return;

    const int tid  = threadIdx.x;
    const int b    = blockIdx.x & 7;        // XCD-affine batch (136 jobs/batch)
    int rem        = blockIdx.x >> 3;       // 0..135
    const int w    = tid >> 6;
    const int lane = tid & 63, lx = lane & 15, lg = lane >> 4;

    // decode: 128-row band g (0..15) has 16-g tiles
    int g = 0;
    while (rem >= 16 - g) { rem -= 16 - g; g++; }
    const int st   = g + rem;               // shared s-tile for all 4 waves
    const int s0   = 128 * st;
    const int g16b = 8 * g + 2 * w;         // wave's first 16-row group
    const int m0   = 128 * g + 32 * w;      // wave's first row

    const f4 fz = {0.f, 0.f, 0.f, 0.f};
    f4 sa[2][8];
    #pragma unroll
    for (int rg = 0; rg < 2; rg++)
        #pragma unroll
        for (int nt = 0; nt < 8; nt++) sa[rg][nt] = fz;

    const size_t qoff = ((size_t)(b * 128 + g16b) * 16) * 256 + (size_t)lane * 4;
    const size_t koff = ((size_t)(b * 16 + st) * 128) * 256 + (size_t)lane * 4;

    #pragma unroll
    for (int t = 0; t < 16; t++) {
        h8 ah[2], al[2];
        #pragma unroll
        for (int rg = 0; rg < 2; rg++) {
            ah[rg] = __builtin_bit_cast(h8, *(const u4v*)(Qh + qoff + (size_t)(rg * 16 + t) * 256));
            al[rg] = __builtin_bit_cast(h8, *(const u4v*)(Ql + qoff + (size_t)(rg * 16 + t) * 256));
        }
        h8 kh[8], kl[8];
        #pragma unroll
        for (int nt = 0; nt < 8; nt++) {
            kh[nt] = __builtin_bit_cast(h8, *(const u4v*)(Kh + koff + (size_t)(t * 8 + nt) * 256));
            kl[nt] = __builtin_bit_cast(h8, *(const u4v*)(Kl + koff + (size_t)(t * 8 + nt) * 256));
        }
        __builtin_amdgcn_s_setprio(1);
        #pragma unroll
        for (int nt = 0; nt < 8; nt++) {
            #pragma unroll
            for (int rg = 0; rg < 2; rg++) {
                sa[rg][nt] = MFMA16(ah[rg], kh[nt], sa[rg][nt]);
                sa[rg][nt] = MFMA16(ah[rg], kl[nt], sa[rg][nt]);
                sa[rg][nt] = MFMA16(al[rg], kh[nt], sa[rg][nt]);
            }
        }
        __builtin_amdgcn_s_setprio(0);
    }

    // ---- NaN scrub (insurance) + masked argmin + atomicMin (per 16-row grp) ----
    #pragma unroll
    for (int rg = 0; rg < 2; rg++) {
        #pragma unroll
        for (int nt = 0; nt < 8; nt++)
            #pragma unroll
            for (int r = 0; r < 4; r++) {
                float s = sa[rg][nt][r];
                sa[rg][nt][r] = (s == s) ? s : 0.0f;
            }
        #pragma unroll
        for (int r = 0; r < 4; r++) {
            const int tg = m0 + 16 * rg + 4 * lg + r;
            float mv = INFINITY; int mi = -1;
            #pragma unroll
            for (int nt = 0; nt < 8; nt++) {
                const int sg = s0 + 16 * nt + lx;
                const float v = sa[rg][nt][r];
                if (sg >= tg && v < mv) { mv = v; mi = sg; }
            }
            #pragma unroll
            for (int off = 1; off < 16; off <<= 1) {
                const float ov = __shfl_xor(mv, off);
                const int   oi = __shfl_xor(mi, off);
                if (ov < mv || (ov == mv && oi >= 0 && (mi < 0 || oi < mi))) { mv = ov; mi = oi; }
            }
            if (lx == 0 && mi >= 0) {
                const u64 pk = ((u64)fkey(mv) << 32) | (u32)mi;
                atomicMin(&keys[(size_t)b * SEQ + tg], pk);
            }
        }
    }
}

// ================= argmin_lds: R11-verbatim fallback (small ws) =================
__global__ __launch_bounds__(512, 2)
void argmin_lds_kernel(const float* __restrict__ Q, const float* __restrict__ K,
                       const int* __restrict__ mfp, u64* __restrict__ ws)
{
    if (mfp[0] == 0) return;
    __shared__ u32 KTh[2][128][32];
    __shared__ u32 KTl[2][128][32];
    __shared__ float sx[128][68];

    const int tid  = threadIdx.x;
    const int w    = tid >> 6, wp = w & 3, h = w >> 2;
    const int lane = tid & 63, lx = lane & 15, lg = lane >> 4;

    int j = blockIdx.x;
    const int b = j / 272; j -= b * 272;
    int mg = 0;
    while (true) { const int n = 16 - (mg >> 1); if (j < n) break; j -= n; mg++; }
    const int m0 = mg * 64;
    const int s0 = (m0 & ~127) + 128 * j;

    const float* __restrict__ Qb = Q + (size_t)b * SEQ * DIM;
    const float* __restrict__ Kb = K + (size_t)b * SEQ * DIM;
    const int krow = (tid >> 1) & 127;
    const int ksc  = tid & 1;

    h8 qh[8], ql[8];
    {
        const float* qrowp = Qb + (size_t)(m0 + 16 * wp + lx) * DIM;
        #pragma unroll
        for (int t = 0; t < 8; t++) {
            float bufv[8];
            *(f4*)&bufv[0] = *(const f4*)(qrowp + 256 * h + 32 * t + 8 * lg);
            *(f4*)&bufv[4] = *(const f4*)(qrowp + 256 * h + 32 * t + 8 * lg + 4);
            u4v uh, ul;
            #pragma unroll
            for (int p = 0; p < 4; p++) {
                const HL hl = split2t(bufv[2*p], bufv[2*p+1]);
                uh[p] = hl.hi; ul[p] = hl.lo;
            }
            qh[t] = __builtin_bit_cast(h8, uh);
            ql[t] = __builtin_bit_cast(h8, ul);
        }
    }
    const f4 fz = {0.f, 0.f, 0.f, 0.f};
    f4 sa[8];
    #pragma unroll
    for (int nt = 0; nt < 8; nt++) sa[nt] = fz;

    f4 kreg[8];
    #pragma unroll
    for (int c = 0; c < 8; c++)
        kreg[c] = *(const f4*)(Kb + (size_t)(s0 + krow) * DIM + 256 * h + 32 * ksc + 4 * c);

    #pragma unroll
    for (int i = 0; i < 4; i++) {
        if (i) __syncthreads();
        {
            u32 HH[16], LL[16];
            #pragma unroll
            for (int c = 0; c < 8; c++) {
                const HL e0 = split2t(kreg[c][0], kreg[c][1]);
                const HL e1 = split2t(kreg[c][2], kreg[c][3]);
                HH[2*c] = e0.hi;   LL[2*c] = e0.lo;
                HH[2*c+1] = e1.hi; LL[2*c+1] = e1.lo;
            }
            #pragma unroll
            for (int qd = 0; qd < 4; qd++) {
                const int gp = ((4 * ksc + qd) ^ (krow & 7)) * 4;
                u4v vh = {HH[4*qd], HH[4*qd+1], HH[4*qd+2], HH[4*qd+3]};
                u4v vl = {LL[4*qd], LL[4*qd+1], LL[4*qd+2], LL[4*qd+3]};
                *(u4v*)&KTh[h][krow][gp] = vh;
                *(u4v*)&KTl[h][krow][gp] = vl;
            }
        }
        __syncthreads();
        if (i < 3) {
            #pragma unroll
            for (int c = 0; c < 8; c++)
                kreg[c] = *(const f4*)(Kb + (size_t)(s0 + krow) * DIM
                                       + 256 * h + 64 * (i + 1) + 32 * ksc + 4 * c);
        }
        __builtin_amdgcn_s_setprio(1);
        #pragma unroll
        for (int tl = 0; tl < 2; tl++) {
            const int t = 2 * i + tl;
            #pragma unroll
            for (int nt = 0; nt < 8; nt++) {
                const int s  = 16 * nt + lx;
                const int gp = ((4 * tl + lg) ^ (s & 7)) * 4;
                const h8 kh = __builtin_bit_cast(h8, *(const u4v*)&KTh[h][s][gp]);
                const h8 kl = __builtin_bit_cast(h8, *(const u4v*)&KTl[h][s][gp]);
                sa[nt] = MFMA16(qh[t], kh, sa[nt]);
                sa[nt] = MFMA16(qh[t], kl, sa[nt]);
                sa[nt] = MFMA16(ql[t], kh, sa[nt]);
            }
        }
        __builtin_amdgcn_s_setprio(0);
    }

    if (h == 0) {
        #pragma unroll
        for (int nt = 0; nt < 8; nt++)
            *(f4*)&sx[16 * nt + lx][16 * wp + 4 * lg] = sa[nt];
    }
    __syncthreads();
    if (h == 1) {
        #pragma unroll
        for (int nt = 0; nt < 8; nt++) {
            const f4 part = *(const f4*)&sx[16 * nt + lx][16 * wp + 4 * lg];
            #pragma unroll
            for (int r = 0; r < 4; r++) {
                float s = sa[nt][r] + part[r];
                sa[nt][r] = (s == s) ? s : 0.0f;
            }
        }
        #pragma unroll
        for (int r = 0; r < 4; r++) {
            const int tg = m0 + 16 * wp + 4 * lg + r;
            float mv = INFINITY; int mi = -1;
            #pragma unroll
            for (int nt = 0; nt < 8; nt++) {
                const int sg = s0 + 16 * nt + lx;
                const float v = sa[nt][r];
                if (sg >= tg && v < mv) { mv = v; mi = sg; }
            }
            #pragma unroll
            for (int off = 1; off < 16; off <<= 1) {
                const float ov = __shfl_xor(mv, off);
                const int   oi = __shfl_xor(mi, off);
                if (ov < mv || (ov == mv && oi >= 0 && (mi < 0 || oi < mi))) { mv = ov; mi = oi; }
            }
            if (lx == 0 && mi >= 0) {
                const u64 pk = ((u64)fkey(mv) << 32) | (u32)mi;
                atomicMin(&ws[(size_t)b * SEQ + tg], pk);
            }
        }
    }
}

// ================= gather + worklist (R10-verbatim) =================
__global__ __launch_bounds__(512, 2)
void gather_kernel(const float* __restrict__ V, const u64* __restrict__ keys,
                   u32* __restrict__ cnt, u32* __restrict__ list,
                   float* __restrict__ Out)
{
    const int tid  = threadIdx.x;
    const int w    = tid >> 6;
    const int lane = tid & 63;
    const int b    = blockIdx.x >> 5;
    const int m0   = (blockIdx.x & 31) * 64;

    const float* __restrict__ Vb = V + (size_t)b * SEQ * DIM;
    float* __restrict__ Ob = Out + (size_t)b * SEQ * DIM;

    #pragma unroll
    for (int rr = 0; rr < 8; rr++) {
        const int tg = m0 + 8 * w + rr;
        const u64 pk = keys[(size_t)b * SEQ + tg];
        const u32 key = (u32)(pk >> 32);
        if (key < 0x80000000u) {
            const int ss = (int)(pk & 0xFFFFFFFFu);
            #pragma unroll
            for (int it = 0; it < 2; it++) {
                const int col = 256 * it + 4 * lane;
                *(f4*)(Ob + (size_t)tg * DIM + col) = *(const f4*)(Vb + (size_t)ss * DIM + col);
            }
        } else if (lane == 0) {
            const u32 p = atomicAdd(cnt, 1u);
            list[p] = ((u32)b << 16) | (u32)tg;
        }
    }
}

// ====== fb_part (R11-verbatim) ======
__global__ __launch_bounds__(512, 2)
void fb_part_kernel(const float* __restrict__ Q, const float* __restrict__ K,
                    const float* __restrict__ V, const int* __restrict__ mfp,
                    const u32* __restrict__ cnt, const u32* __restrict__ list,
                    float2* __restrict__ meta, float* __restrict__ partials)
{
    __shared__ float qrow[DIM];
    __shared__ float zpart[4][CHW];
    __shared__ float zs[CHW];
    __shared__ float zp[CHW];
    __shared__ f4    pacc[4][128];
    __shared__ float red2[2];

    const int tid = threadIdx.x;
    const int mf  = mfp[0];
    const float dk = 22.627416997969522f;

    const int n  = (int)cnt[0];
    const int nw = min(n * NCH, CAP);

    for (int wi = blockIdx.x; wi < nw; wi += gridDim.x) {
        const int ridx  = wi >> 4;
        const int chunk = wi & 15;
        const u32 e  = list[ridx];
        const int b  = (int)(e >> 16);
        const int tg = (int)(e & 0xFFFFu);

        const float* __restrict__ Qb = Q + (size_t)b * SEQ * DIM;
        const float* __restrict__ Kb = K + (size_t)b * SEQ * DIM;
        const float* __restrict__ Vb = V + (size_t)b * SEQ * DIM;

        if (tid < 128) *(f4*)&qrow[4 * tid] = *(const f4*)(Qb + (size_t)tg * DIM + 4 * tid);
        __syncthreads();
        {
            const int jj   = tid & 127;
            const int dseg = tid >> 7;
            const int col  = chunk * CHW + jj;
            const float* kr = Kb + (size_t)col * DIM + 128 * dseg;
            float acc = 0.f;
            #pragma unroll 8
            for (int d4 = 0; d4 < 32; d4++) {
                const f4 q = *(const f4*)&qrow[4 * (32 * dseg + d4)];
                const f4 k = *(const f4*)(kr + 4 * d4);
                acc += q[0]*k[0] + q[1]*k[1] + q[2]*k[2] + q[3]*k[3];
            }
            zpart[dseg][jj] = acc;
        }
        __syncthreads();
        if (tid < 128) {
            const int col = chunk * CHW + tid;
            float z = zpart[0][tid] + zpart[1][tid] + zpart[2][tid] + zpart[3][tid];
            const float mult = (mf && col >= tg) ? -1.0e9f : 1.0f;
            zs[tid] = z * mult / dk;
        }
        __syncthreads();
        if (tid < 64) {
            float m = fmaxf(zs[tid], zs[tid + 64]);
            #pragma unroll
            for (int off = 1; off < 64; off <<= 1) m = fmaxf(m, __shfl_xor(m, off));
            if (tid == 0) red2[0] = m;
        }
        __syncthreads();
        const float M = red2[0];
        if (tid < 128) zp[tid] = expf(zs[tid] - M);
        __syncthreads();
        if (tid < 64) {
            float s = zp[tid] + zp[tid + 64];
            #pragma unroll
            for (int off = 1; off < 64; off <<= 1) s += __shfl_xor(s, off);
            if (tid == 0) red2[1] = s;
        }
        {
            const int dq   = tid & 127;
            const int sseg = tid >> 7;
            f4 acc = {0.f, 0.f, 0.f, 0.f};
            const int sb = chunk * CHW + 32 * sseg;
            #pragma unroll 8
            for (int s = 0; s < 32; s++)
                acc += zp[32 * sseg + s] * *(const f4*)(Vb + (size_t)(sb + s) * DIM + 4 * dq);
            pacc[sseg][dq] = acc;
        }
        __syncthreads();
        if (tid < 128) {
            const f4 nc = pacc[0][tid] + pacc[1][tid] + pacc[2][tid] + pacc[3][tid];
            *(f4*)&partials[(size_t)wi * DIM + 4 * tid] = nc;
        }
        if (tid == 0) meta[wi] = make_float2(M, red2[1]);
        __syncthreads();
    }
}

// ====== fb_combine (R11-verbatim) ======
__global__ __launch_bounds__(512, 2)
void fb_combine_kernel(const float* __restrict__ Q, const float* __restrict__ K,
                       const float* __restrict__ V, const int* __restrict__ mfp,
                       const u32* __restrict__ cnt, const u32* __restrict__ list,
                       const float2* __restrict__ meta, const float* __restrict__ partials,
                       float* __restrict__ Out)
{
    __shared__ float qrow[DIM];
    __shared__ float zrow[SEQ];
    __shared__ float red[8];
    __shared__ f4    pacc[4][128];

    const int tid  = threadIdx.x;
    const int w    = tid >> 6;
    const int lane = tid & 63;
    const int mf   = mfp[0];
    const float dk = 22.627416997969522f;

    const int n = (int)cnt[0];
    for (int idx = blockIdx.x; idx < n; idx += gridDim.x) {
        const u32 e  = list[idx];
        const int b  = (int)(e >> 16);
        const int tg = (int)(e & 0xFFFFu);
        float* __restrict__ Ob = Out + (size_t)b * SEQ * DIM;

        if (idx < CAP / NCH) {
            float M = -INFINITY;
            #pragma unroll
            for (int c = 0; c < NCH; c++) M = fmaxf(M, meta[idx * NCH + c].x);
            float L = 0.f, o = 0.f;
            #pragma unroll
            for (int c = 0; c < NCH; c++) {
                const float2 mc = meta[idx * NCH + c];
                const float fct = expf(mc.x - M);
                L += mc.y * fct;
                o += partials[(size_t)(idx * NCH + c) * DIM + tid] * fct;
            }
            Ob[(size_t)tg * DIM + tid] = o / L;
        } else {
            const float* __restrict__ Qb = Q + (size_t)b * SEQ * DIM;
            const float* __restrict__ Kb = K + (size_t)b * SEQ * DIM;
            const float* __restrict__ Vb = V + (size_t)b * SEQ * DIM;
            if (tid < 128) *(f4*)&qrow[4 * tid] = *(const f4*)(Qb + (size_t)tg * DIM + 4 * tid);
            __syncthreads();
            float z4[4];
            #pragma unroll
            for (int c4 = 0; c4 < 4; c4++) {
                const int col = tid + 512 * c4;
                const float* kr = Kb + (size_t)col * DIM;
                float acc = 0.f;
                #pragma unroll 4
                for (int d4 = 0; d4 < 128; d4++) {
                    const f4 q = *(const f4*)&qrow[4 * d4];
                    const f4 k = *(const f4*)(kr + 4 * d4);
                    acc += q[0]*k[0] + q[1]*k[1] + q[2]*k[2] + q[3]*k[3];
                }
                const float mult = (mf && col >= tg) ? -1.0e9f : 1.0f;
                z4[c4] = acc * mult / dk;
            }
            float lm = fmaxf(fmaxf(z4[0], z4[1]), fmaxf(z4[2], z4[3]));
            #pragma unroll
            for (int off = 1; off < 64; off <<= 1) lm = fmaxf(lm, __shfl_xor(lm, off));
            if (lane == 0) red[w] = lm;
            __syncthreads();
            float M = red[0];
            #pragma unroll
            for (int i = 1; i < 8; i++) M = fmaxf(M, red[i]);
            float ls = 0.f;
            #pragma unroll
            for (int c4 = 0; c4 < 4; c4++) {
                const float p = expf(z4[c4] - M);
                zrow[tid + 512 * c4] = p;
                ls += p;
            }
            #pragma unroll
            for (int off = 1; off < 64; off <<= 1) ls += __shfl_xor(ls, off);
            __syncthreads();
            if (lane == 0) red[w] = ls;
            __syncthreads();
            float L = 0.f;
            #pragma unroll
            for (int i = 0; i < 8; i++) L += red[i];
            const int dq = tid & 127;
            const int sq = tid >> 7;
            f4 acc = {0.f, 0.f, 0.f, 0.f};
            const int sbeg = 512 * sq;
            #pragma unroll 8
            for (int s = 0; s < 512; s++)
                acc += zrow[sbeg + s] * *(const f4*)(Vb + (size_t)(sbeg + s) * DIM + 4 * dq);
            pacc[sq][dq] = acc;
            __syncthreads();
            if (tid < 128) {
                f4 r = pacc[0][tid] + pacc[1][tid] + pacc[2][tid] + pacc[3][tid];
                const float il = 1.0f / L;
                r[0] *= il; r[1] *= il; r[2] *= il; r[3] *= il;
                *(f4*)(Ob + (size_t)tg * DIM + 4 * tid) = r;
            }
            __syncthreads();
        }
    }
}

extern "C" void kernel_launch(void* const* d_in, const int* in_sizes, int n_in,
                              void* d_out, int out_size, void* d_ws, size_t ws_size,
                              hipStream_t stream) {
    const float* Q  = (const float*)d_in[0];
    const float* K  = (const float*)d_in[1];
    const float* V  = (const float*)d_in[2];
    const int*   mf = (const int*)d_in[3];
    float* O = (float*)d_out;

    char* wsb = (char*)d_ws;
    u64*    keys     = (u64*)wsb;                                   // 128 KB
    u32*    cnt      = (u32*)(wsb + 131072);
    u32*    list     = (u32*)(wsb + 131072 + 256);                  // 64 KB
    float2* meta     = (float2*)(wsb + 131072 + 256 + 65536);       // 4 KB
    float*  partials = (float*)(wsb + 131072 + 256 + 65536 + 8192); // 1 MB

    const size_t SPLIT_OFF = 1310720;                 // 1.25 MB, 16B-aligned
    const size_t ARR = (size_t)BATCH * SEQ * 256 * 4; // 16 MB per array
    u32* Qh = (u32*)(wsb + SPLIT_OFF);
    u32* Ql = (u32*)(wsb + SPLIT_OFF + ARR);
    u32* Kh = (u32*)(wsb + SPLIT_OFF + 2 * ARR);
    u32* Kl = (u32*)(wsb + SPLIT_OFF + 3 * ARR);
    const bool big_ws = ws_size >= SPLIT_OFF + 4 * ARR;

    hipMemsetAsync(keys, 0xFF, (size_t)BATCH * SEQ * sizeof(u64), stream);
    hipMemsetAsync(cnt, 0, sizeof(u32), stream);

    if (big_ws) {
        prep_kernel<<<dim3(3072), dim3(256), 0, stream>>>(Q, K, Qh, Ql, Kh, Kl);
        argmin4_kernel<<<dim3(1088), dim3(256), 0, stream>>>(Qh, Ql, Kh, Kl, mf, keys);
    } else {
        argmin_lds_kernel<<<dim3(BATCH * 272), dim3(512), 0, stream>>>(Q, K, mf, keys);
    }
    gather_kernel<<<dim3(BATCH * (SEQ / 64)), dim3(512), 0, stream>>>(V, keys, cnt, list, O);
    fb_part_kernel<<<dim3(512), dim3(512), 0, stream>>>(Q, K, V, mf, cnt, list, meta, partials);
    fb_combine_kernel<<<dim3(128), dim3(512), 0, stream>>>(Q, K, V, mf, cnt, list, meta, partials, O);
}

// Round 20
// 122.414 us; speedup vs baseline: 2.3485x; 1.0569x over previous
//
#include <hip/hip_runtime.h>
#include <math.h>

#define BATCH 8
#define SEQ   2048
#define DIM   512
#define NCH   16
#define CHW   128
#define CAP   512

typedef unsigned int u32;
typedef unsigned long long u64;
typedef _Float16 h2  __attribute__((ext_vector_type(2)));
typedef _Float16 h8  __attribute__((ext_vector_type(8)));
typedef float    f4  __attribute__((ext_vector_type(4)));
typedef u32      u4v __attribute__((ext_vector_type(4)));

#define MFMA16(a,b,c) __builtin_amdgcn_mfma_f32_16x16x32_f16((a),(b),(c),0,0,0)

struct HL { u32 hi, lo; };
__device__ __forceinline__ HL split2t(float a, float b) {
    _Float16 ha = (_Float16)a, hb = (_Float16)b;
    h2 th; th[0] = ha; th[1] = hb;
    h2 tl; tl[0] = (_Float16)(a - (float)ha); tl[1] = (_Float16)(b - (float)hb);
    HL r; r.hi = __builtin_bit_cast(u32, th); r.lo = __builtin_bit_cast(u32, tl);
    return r;
}
__device__ __forceinline__ u32 fkey(float f) {
    u32 v = __builtin_bit_cast(u32, f);
    return (v & 0x80000000u) ? ~v : (v | 0x80000000u);
}
__device__ __forceinline__ void gload_lds16(const u32* gsrc, u32* ldst) {
    __builtin_amdgcn_global_load_lds(
        (const __attribute__((address_space(1))) void*)gsrc,
        (__attribute__((address_space(3))) void*)ldst, 16, 0, 0);
}

// ==== fused prep: blocks 0..1023 do Q, 1024..3071 do K (R18-verbatim) ====
__global__ __launch_bounds__(256, 4)
void prep_kernel(const float* __restrict__ Q, const float* __restrict__ K,
                 u32* __restrict__ Qh, u32* __restrict__ Ql,
                 u32* __restrict__ Kh, u32* __restrict__ Kl)
{
    const int lane = threadIdx.x & 63;
    const int lx   = lane & 15, lg = lane >> 4;
    if (blockIdx.x < 1024) {
        const int b    = blockIdx.x >> 7;
        const int g16  = blockIdx.x & 127;
        const int tq   = threadIdx.x >> 6;
        const float* src0 = Q + ((size_t)(b * SEQ + g16 * 16 + lx)) * DIM + 8 * lg;
        #pragma unroll
        for (int p = 0; p < 4; p++) {
            const int t = p * 4 + tq;
            const float* s = src0 + 32 * t;
            const f4 r0 = *(const f4*)(s);
            const f4 r1 = *(const f4*)(s + 4);
            const HL p0 = split2t(r0[0], r0[1]);
            const HL p1 = split2t(r0[2], r0[3]);
            const HL p2 = split2t(r1[0], r1[1]);
            const HL p3 = split2t(r1[2], r1[3]);
            u4v vh = {p0.hi, p1.hi, p2.hi, p3.hi};
            u4v vl = {p0.lo, p1.lo, p2.lo, p3.lo};
            const size_t off = (((size_t)(b * 128 + g16) * 16 + t) * 256) + (size_t)lane * 4;
            *(u4v*)(Qh + off) = vh;
            *(u4v*)(Ql + off) = vl;
        }
    } else {
        const int blk  = blockIdx.x - 1024;
        const int b    = blk >> 8;
        const int st   = (blk >> 4) & 15;
        const int t    = blk & 15;
        const int nq   = threadIdx.x >> 6;
        #pragma unroll
        for (int p = 0; p < 2; p++) {
            const int nt = p * 4 + nq;
            const float* s = K + ((size_t)(b * SEQ + 128 * st + 16 * nt + lx)) * DIM + 32 * t + 8 * lg;
            const f4 r0 = *(const f4*)(s);
            const f4 r1 = *(const f4*)(s + 4);
            const HL p0 = split2t(r0[0], r0[1]);
            const HL p1 = split2t(r0[2], r0[3]);
            const HL p2 = split2t(r1[0], r1[1]);
            const HL p3 = split2t(r1[2], r1[3]);
            u4v vh = {p0.hi, p1.hi, p2.hi, p3.hi};
            u4v vl = {p0.lo, p1.lo, p2.lo, p3.lo};
            const size_t off = ((((size_t)(b * 16 + st) * 16 + t) * 8 + nt) * 256) + (size_t)lane * 4;
            *(u4v*)(Kh + off) = vh;
            *(u4v*)(Kl + off) = vl;
        }
    }
}

// ===== argmin5: T3/T4 counted-vmcnt pipeline. Block = 128 rows x 1 s-tile,
// K staged ONCE per block into 3x16KB LDS bufs via global_load_lds; per t-step:
// vmcnt(8) [never 0] -> raw s_barrier -> issue stage(t+2) -> prefetch Q(t+1) ->
// 16x ds_read_b128 + 48 MFMA. Maps (R5-R19 validated).
__global__ __launch_bounds__(256, 2)
void argmin5_kernel(const u32* __restrict__ Qh, const u32* __restrict__ Ql,
                    const u32* __restrict__ Kh, const u32* __restrict__ Kl,
                    const int* __restrict__ mfp, u64* __restrict__ keys)
{
    if (mfp[0] == 0) return;

    __shared__ u32 Kbuf[3][16][256];   // 48KB: [buf][chunk: nt=hi, 8+nt=lo][lane*4]

    const int tid  = threadIdx.x;
    const int b    = blockIdx.x & 7;        // XCD-affine batch (136 jobs/batch)
    int rem        = blockIdx.x >> 3;       // 0..135
    const int w    = tid >> 6;
    const int lane = tid & 63, lx = lane & 15, lg = lane >> 4;

    int g = 0;
    while (rem >= 16 - g) { rem -= 16 - g; g++; }
    const int st   = g + rem;
    const int s0   = 128 * st;
    const int g16b = 8 * g + 2 * w;
    const int m0   = 128 * g + 32 * w;

    const size_t qoff  = ((size_t)(b * 128 + g16b) * 16) * 256 + (size_t)lane * 4;
    const size_t koffu = ((size_t)(b * 16 + st) * 128) * 256;

    // wave w stages chunks c = 4w..4w+3 of step t into Kbuf[t%3]
    auto STAGE = [&](int t) {
        #pragma unroll
        for (int c4 = 0; c4 < 4; c4++) {
            const int c  = 4 * w + c4;
            const int nt = c & 7;
            const u32* src = ((c < 8) ? Kh : Kl) + koffu
                             + (size_t)(t * 8 + nt) * 256 + (size_t)lane * 4;
            gload_lds16(src, &Kbuf[t % 3][c][0]);
        }
    };

    const f4 fz = {0.f, 0.f, 0.f, 0.f};
    f4 sa[2][8];
    #pragma unroll
    for (int rg = 0; rg < 2; rg++)
        #pragma unroll
        for (int nt = 0; nt < 8; nt++) sa[rg][nt] = fz;

    h8 qhr[2][2], qlr[2][2];   // [t&1][rg] — static indices under full unroll

    // ---- prologue: stage t=0,1; load Q(0) ----
    STAGE(0);
    STAGE(1);
    #pragma unroll
    for (int rg = 0; rg < 2; rg++) {
        qhr[0][rg] = __builtin_bit_cast(h8, *(const u4v*)(Qh + qoff + (size_t)(rg * 16) * 256));
        qlr[0][rg] = __builtin_bit_cast(h8, *(const u4v*)(Ql + qoff + (size_t)(rg * 16) * 256));
    }

    #pragma unroll
    for (int t = 0; t < 16; t++) {
        // own stage(t) done (stage(t+1)+Q(t)=8 newer stay in flight); then all
        // waves' stage(t) visible after barrier.
        asm volatile("s_waitcnt vmcnt(8)" ::: "memory");
        __builtin_amdgcn_s_barrier();
        asm volatile("" ::: "memory");
        if (t < 14) STAGE(t + 2);
        if (t < 15) {
            #pragma unroll
            for (int rg = 0; rg < 2; rg++) {
                qhr[(t + 1) & 1][rg] = __builtin_bit_cast(h8,
                    *(const u4v*)(Qh + qoff + (size_t)(rg * 16 + t + 1) * 256));
                qlr[(t + 1) & 1][rg] = __builtin_bit_cast(h8,
                    *(const u4v*)(Ql + qoff + (size_t)(rg * 16 + t + 1) * 256));
            }
        }
        __builtin_amdgcn_s_setprio(1);
        #pragma unroll
        for (int nt = 0; nt < 8; nt++) {
            const h8 kh = __builtin_bit_cast(h8, *(const u4v*)&Kbuf[t % 3][nt][4 * lane]);
            const h8 kl = __builtin_bit_cast(h8, *(const u4v*)&Kbuf[t % 3][8 + nt][4 * lane]);
            #pragma unroll
            for (int rg = 0; rg < 2; rg++) {
                sa[rg][nt] = MFMA16(qhr[t & 1][rg], kh, sa[rg][nt]);
                sa[rg][nt] = MFMA16(qhr[t & 1][rg], kl, sa[rg][nt]);
                sa[rg][nt] = MFMA16(qlr[t & 1][rg], kh, sa[rg][nt]);
            }
        }
        __builtin_amdgcn_s_setprio(0);
    }

    // ---- NaN scrub (insurance) + masked argmin + atomicMin (per 16-row grp) ----
    #pragma unroll
    for (int rg = 0; rg < 2; rg++) {
        #pragma unroll
        for (int nt = 0; nt < 8; nt++)
            #pragma unroll
            for (int r = 0; r < 4; r++) {
                float s = sa[rg][nt][r];
                sa[rg][nt][r] = (s == s) ? s : 0.0f;
            }
        #pragma unroll
        for (int r = 0; r < 4; r++) {
            const int tg = m0 + 16 * rg + 4 * lg + r;
            float mv = INFINITY; int mi = -1;
            #pragma unroll
            for (int nt = 0; nt < 8; nt++) {
                const int sg = s0 + 16 * nt + lx;
                const float v = sa[rg][nt][r];
                if (sg >= tg && v < mv) { mv = v; mi = sg; }
            }
            #pragma unroll
            for (int off = 1; off < 16; off <<= 1) {
                const float ov = __shfl_xor(mv, off);
                const int   oi = __shfl_xor(mi, off);
                if (ov < mv || (ov == mv && oi >= 0 && (mi < 0 || oi < mi))) { mv = ov; mi = oi; }
            }
            if (lx == 0 && mi >= 0) {
                const u64 pk = ((u64)fkey(mv) << 32) | (u32)mi;
                atomicMin(&keys[(size_t)b * SEQ + tg], pk);
            }
        }
    }
}

// ================= argmin_lds: R11-verbatim fallback (small ws) =================
__global__ __launch_bounds__(512, 2)
void argmin_lds_kernel(const float* __restrict__ Q, const float* __restrict__ K,
                       const int* __restrict__ mfp, u64* __restrict__ ws)
{
    if (mfp[0] == 0) return;
    __shared__ u32 KTh[2][128][32];
    __shared__ u32 KTl[2][128][32];
    __shared__ float sx[128][68];

    const int tid  = threadIdx.x;
    const int w    = tid >> 6, wp = w & 3, h = w >> 2;
    const int lane = tid & 63, lx = lane & 15, lg = lane >> 4;

    int j = blockIdx.x;
    const int b = j / 272; j -= b * 272;
    int mg = 0;
    while (true) { const int n = 16 - (mg >> 1); if (j < n) break; j -= n; mg++; }
    const int m0 = mg * 64;
    const int s0 = (m0 & ~127) + 128 * j;

    const float* __restrict__ Qb = Q + (size_t)b * SEQ * DIM;
    const float* __restrict__ Kb = K + (size_t)b * SEQ * DIM;
    const int krow = (tid >> 1) & 127;
    const int ksc  = tid & 1;

    h8 qh[8], ql[8];
    {
        const float* qrowp = Qb + (size_t)(m0 + 16 * wp + lx) * DIM;
        #pragma unroll
        for (int t = 0; t < 8; t++) {
            float bufv[8];
            *(f4*)&bufv[0] = *(const f4*)(qrowp + 256 * h + 32 * t + 8 * lg);
            *(f4*)&bufv[4] = *(const f4*)(qrowp + 256 * h + 32 * t + 8 * lg + 4);
            u4v uh, ul;
            #pragma unroll
            for (int p = 0; p < 4; p++) {
                const HL hl = split2t(bufv[2*p], bufv[2*p+1]);
                uh[p] = hl.hi; ul[p] = hl.lo;
            }
            qh[t] = __builtin_bit_cast(h8, uh);
            ql[t] = __builtin_bit_cast(h8, ul);
        }
    }
    const f4 fz = {0.f, 0.f, 0.f, 0.f};
    f4 sa[8];
    #pragma unroll
    for (int nt = 0; nt < 8; nt++) sa[nt] = fz;

    f4 kreg[8];
    #pragma unroll
    for (int c = 0; c < 8; c++)
        kreg[c] = *(const f4*)(Kb + (size_t)(s0 + krow) * DIM + 256 * h + 32 * ksc + 4 * c);

    #pragma unroll
    for (int i = 0; i < 4; i++) {
        if (i) __syncthreads();
        {
            u32 HH[16], LL[16];
            #pragma unroll
            for (int c = 0; c < 8; c++) {
                const HL e0 = split2t(kreg[c][0], kreg[c][1]);
                const HL e1 = split2t(kreg[c][2], kreg[c][3]);
                HH[2*c] = e0.hi;   LL[2*c] = e0.lo;
                HH[2*c+1] = e1.hi; LL[2*c+1] = e1.lo;
            }
            #pragma unroll
            for (int qd = 0; qd < 4; qd++) {
                const int gp = ((4 * ksc + qd) ^ (krow & 7)) * 4;
                u4v vh = {HH[4*qd], HH[4*qd+1], HH[4*qd+2], HH[4*qd+3]};
                u4v vl = {LL[4*qd], LL[4*qd+1], LL[4*qd+2], LL[4*qd+3]};
                *(u4v*)&KTh[h][krow][gp] = vh;
                *(u4v*)&KTl[h][krow][gp] = vl;
            }
        }
        __syncthreads();
        if (i < 3) {
            #pragma unroll
            for (int c = 0; c < 8; c++)
                kreg[c] = *(const f4*)(Kb + (size_t)(s0 + krow) * DIM
                                       + 256 * h + 64 * (i + 1) + 32 * ksc + 4 * c);
        }
        __builtin_amdgcn_s_setprio(1);
        #pragma unroll
        for (int tl = 0; tl < 2; tl++) {
            const int t = 2 * i + tl;
            #pragma unroll
            for (int nt = 0; nt < 8; nt++) {
                const int s  = 16 * nt + lx;
                const int gp = ((4 * tl + lg) ^ (s & 7)) * 4;
                const h8 kh = __builtin_bit_cast(h8, *(const u4v*)&KTh[h][s][gp]);
                const h8 kl = __builtin_bit_cast(h8, *(const u4v*)&KTl[h][s][gp]);
                sa[nt] = MFMA16(qh[t], kh, sa[nt]);
                sa[nt] = MFMA16(qh[t], kl, sa[nt]);
                sa[nt] = MFMA16(ql[t], kh, sa[nt]);
            }
        }
        __builtin_amdgcn_s_setprio(0);
    }

    if (h == 0) {
        #pragma unroll
        for (int nt = 0; nt < 8; nt++)
            *(f4*)&sx[16 * nt + lx][16 * wp + 4 * lg] = sa[nt];
    }
    __syncthreads();
    if (h == 1) {
        #pragma unroll
        for (int nt = 0; nt < 8; nt++) {
            const f4 part = *(const f4*)&sx[16 * nt + lx][16 * wp + 4 * lg];
            #pragma unroll
            for (int r = 0; r < 4; r++) {
                float s = sa[nt][r] + part[r];
                sa[nt][r] = (s == s) ? s : 0.0f;
            }
        }
        #pragma unroll
        for (int r = 0; r < 4; r++) {
            const int tg = m0 + 16 * wp + 4 * lg + r;
            float mv = INFINITY; int mi = -1;
            #pragma unroll
            for (int nt = 0; nt < 8; nt++) {
                const int sg = s0 + 16 * nt + lx;
                const float v = sa[nt][r];
                if (sg >= tg && v < mv) { mv = v; mi = sg; }
            }
            #pragma unroll
            for (int off = 1; off < 16; off <<= 1) {
                const float ov = __shfl_xor(mv, off);
                const int   oi = __shfl_xor(mi, off);
                if (ov < mv || (ov == mv && oi >= 0 && (mi < 0 || oi < mi))) { mv = ov; mi = oi; }
            }
            if (lx == 0 && mi >= 0) {
                const u64 pk = ((u64)fkey(mv) << 32) | (u32)mi;
                atomicMin(&ws[(size_t)b * SEQ + tg], pk);
            }
        }
    }
}

// ================= gather + worklist (R10-verbatim) =================
__global__ __launch_bounds__(512, 2)
void gather_kernel(const float* __restrict__ V, const u64* __restrict__ keys,
                   u32* __restrict__ cnt, u32* __restrict__ list,
                   float* __restrict__ Out)
{
    const int tid  = threadIdx.x;
    const int w    = tid >> 6;
    const int lane = tid & 63;
    const int b    = blockIdx.x >> 5;
    const int m0   = (blockIdx.x & 31) * 64;

    const float* __restrict__ Vb = V + (size_t)b * SEQ * DIM;
    float* __restrict__ Ob = Out + (size_t)b * SEQ * DIM;

    #pragma unroll
    for (int rr = 0; rr < 8; rr++) {
        const int tg = m0 + 8 * w + rr;
        const u64 pk = keys[(size_t)b * SEQ + tg];
        const u32 key = (u32)(pk >> 32);
        if (key < 0x80000000u) {
            const int ss = (int)(pk & 0xFFFFFFFFu);
            #pragma unroll
            for (int it = 0; it < 2; it++) {
                const int col = 256 * it + 4 * lane;
                *(f4*)(Ob + (size_t)tg * DIM + col) = *(const f4*)(Vb + (size_t)ss * DIM + col);
            }
        } else if (lane == 0) {
            const u32 p = atomicAdd(cnt, 1u);
            list[p] = ((u32)b << 16) | (u32)tg;
        }
    }
}

// ====== fb_part (R11-verbatim) ======
__global__ __launch_bounds__(512, 2)
void fb_part_kernel(const float* __restrict__ Q, const float* __restrict__ K,
                    const float* __restrict__ V, const int* __restrict__ mfp,
                    const u32* __restrict__ cnt, const u32* __restrict__ list,
                    float2* __restrict__ meta, float* __restrict__ partials)
{
    __shared__ float qrow[DIM];
    __shared__ float zpart[4][CHW];
    __shared__ float zs[CHW];
    __shared__ float zp[CHW];
    __shared__ f4    pacc[4][128];
    __shared__ float red2[2];

    const int tid = threadIdx.x;
    const int mf  = mfp[0];
    const float dk = 22.627416997969522f;

    const int n  = (int)cnt[0];
    const int nw = min(n * NCH, CAP);

    for (int wi = blockIdx.x; wi < nw; wi += gridDim.x) {
        const int ridx  = wi >> 4;
        const int chunk = wi & 15;
        const u32 e  = list[ridx];
        const int b  = (int)(e >> 16);
        const int tg = (int)(e & 0xFFFFu);

        const float* __restrict__ Qb = Q + (size_t)b * SEQ * DIM;
        const float* __restrict__ Kb = K + (size_t)b * SEQ * DIM;
        const float* __restrict__ Vb = V + (size_t)b * SEQ * DIM;

        if (tid < 128) *(f4*)&qrow[4 * tid] = *(const f4*)(Qb + (size_t)tg * DIM + 4 * tid);
        __syncthreads();
        {
            const int jj   = tid & 127;
            const int dseg = tid >> 7;
            const int col  = chunk * CHW + jj;
            const float* kr = Kb + (size_t)col * DIM + 128 * dseg;
            float acc = 0.f;
            #pragma unroll 8
            for (int d4 = 0; d4 < 32; d4++) {
                const f4 q = *(const f4*)&qrow[4 * (32 * dseg + d4)];
                const f4 k = *(const f4*)(kr + 4 * d4);
                acc += q[0]*k[0] + q[1]*k[1] + q[2]*k[2] + q[3]*k[3];
            }
            zpart[dseg][jj] = acc;
        }
        __syncthreads();
        if (tid < 128) {
            const int col = chunk * CHW + tid;
            float z = zpart[0][tid] + zpart[1][tid] + zpart[2][tid] + zpart[3][tid];
            const float mult = (mf && col >= tg) ? -1.0e9f : 1.0f;
            zs[tid] = z * mult / dk;
        }
        __syncthreads();
        if (tid < 64) {
            float m = fmaxf(zs[tid], zs[tid + 64]);
            #pragma unroll
            for (int off = 1; off < 64; off <<= 1) m = fmaxf(m, __shfl_xor(m, off));
            if (tid == 0) red2[0] = m;
        }
        __syncthreads();
        const float M = red2[0];
        if (tid < 128) zp[tid] = expf(zs[tid] - M);
        __syncthreads();
        if (tid < 64) {
            float s = zp[tid] + zp[tid + 64];
            #pragma unroll
            for (int off = 1; off < 64; off <<= 1) s += __shfl_xor(s, off);
            if (tid == 0) red2[1] = s;
        }
        {
            const int dq   = tid & 127;
            const int sseg = tid >> 7;
            f4 acc = {0.f, 0.f, 0.f, 0.f};
            const int sb = chunk * CHW + 32 * sseg;
            #pragma unroll 8
            for (int s = 0; s < 32; s++)
                acc += zp[32 * sseg + s] * *(const f4*)(Vb + (size_t)(sb + s) * DIM + 4 * dq);
            pacc[sseg][dq] = acc;
        }
        __syncthreads();
        if (tid < 128) {
            const f4 nc = pacc[0][tid] + pacc[1][tid] + pacc[2][tid] + pacc[3][tid];
            *(f4*)&partials[(size_t)wi * DIM + 4 * tid] = nc;
        }
        if (tid == 0) meta[wi] = make_float2(M, red2[1]);
        __syncthreads();
    }
}

// ====== fb_combine (R11-verbatim) ======
__global__ __launch_bounds__(512, 2)
void fb_combine_kernel(const float* __restrict__ Q, const float* __restrict__ K,
                       const float* __restrict__ V, const int* __restrict__ mfp,
                       const u32* __restrict__ cnt, const u32* __restrict__ list,
                       const float2* __restrict__ meta, const float* __restrict__ partials,
                       float* __restrict__ Out)
{
    __shared__ float qrow[DIM];
    __shared__ float zrow[SEQ];
    __shared__ float red[8];
    __shared__ f4    pacc[4][128];

    const int tid  = threadIdx.x;
    const int w    = tid >> 6;
    const int lane = tid & 63;
    const int mf   = mfp[0];
    const float dk = 22.627416997969522f;

    const int n = (int)cnt[0];
    for (int idx = blockIdx.x; idx < n; idx += gridDim.x) {
        const u32 e  = list[idx];
        const int b  = (int)(e >> 16);
        const int tg = (int)(e & 0xFFFFu);
        float* __restrict__ Ob = Out + (size_t)b * SEQ * DIM;

        if (idx < CAP / NCH) {
            float M = -INFINITY;
            #pragma unroll
            for (int c = 0; c < NCH; c++) M = fmaxf(M, meta[idx * NCH + c].x);
            float L = 0.f, o = 0.f;
            #pragma unroll
            for (int c = 0; c < NCH; c++) {
                const float2 mc = meta[idx * NCH + c];
                const float fct = expf(mc.x - M);
                L += mc.y * fct;
                o += partials[(size_t)(idx * NCH + c) * DIM + tid] * fct;
            }
            Ob[(size_t)tg * DIM + tid] = o / L;
        } else {
            const float* __restrict__ Qb = Q + (size_t)b * SEQ * DIM;
            const float* __restrict__ Kb = K + (size_t)b * SEQ * DIM;
            const float* __restrict__ Vb = V + (size_t)b * SEQ * DIM;
            if (tid < 128) *(f4*)&qrow[4 * tid] = *(const f4*)(Qb + (size_t)tg * DIM + 4 * tid);
            __syncthreads();
            float z4[4];
            #pragma unroll
            for (int c4 = 0; c4 < 4; c4++) {
                const int col = tid + 512 * c4;
                const float* kr = Kb + (size_t)col * DIM;
                float acc = 0.f;
                #pragma unroll 4
                for (int d4 = 0; d4 < 128; d4++) {
                    const f4 q = *(const f4*)&qrow[4 * d4];
                    const f4 k = *(const f4*)(kr + 4 * d4);
                    acc += q[0]*k[0] + q[1]*k[1] + q[2]*k[2] + q[3]*k[3];
                }
                const float mult = (mf && col >= tg) ? -1.0e9f : 1.0f;
                z4[c4] = acc * mult / dk;
            }
            float lm = fmaxf(fmaxf(z4[0], z4[1]), fmaxf(z4[2], z4[3]));
            #pragma unroll
            for (int off = 1; off < 64; off <<= 1) lm = fmaxf(lm, __shfl_xor(lm, off));
            if (lane == 0) red[w] = lm;
            __syncthreads();
            float M = red[0];
            #pragma unroll
            for (int i = 1; i < 8; i++) M = fmaxf(M, red[i]);
            float ls = 0.f;
            #pragma unroll
            for (int c4 = 0; c4 < 4; c4++) {
                const float p = expf(z4[c4] - M);
                zrow[tid + 512 * c4] = p;
                ls += p;
            }
            #pragma unroll
            for (int off = 1; off < 64; off <<= 1) ls += __shfl_xor(ls, off);
            __syncthreads();
            if (lane == 0) red[w] = ls;
            __syncthreads();
            float L = 0.f;
            #pragma unroll
            for (int i = 0; i < 8; i++) L += red[i];
            const int dq = tid & 127;
            const int sq = tid >> 7;
            f4 acc = {0.f, 0.f, 0.f, 0.f};
            const int sbeg = 512 * sq;
            #pragma unroll 8
            for (int s = 0; s < 512; s++)
                acc += zrow[sbeg + s] * *(const f4*)(Vb + (size_t)(sbeg + s) * DIM + 4 * dq);
            pacc[sq][dq] = acc;
            __syncthreads();
            if (tid < 128) {
                f4 r = pacc[0][tid] + pacc[1][tid] + pacc[2][tid] + pacc[3][tid];
                const float il = 1.0f / L;
                r[0] *= il; r[1] *= il; r[2] *= il; r[3] *= il;
                *(f4*)(Ob + (size_t)tg * DIM + 4 * tid) = r;
            }
            __syncthreads();
        }
    }
}

extern "C" void kernel_launch(void* const* d_in, const int* in_sizes, int n_in,
                              void* d_out, int out_size, void* d_ws, size_t ws_size,
                              hipStream_t stream) {
    const float* Q  = (const float*)d_in[0];
    const float* K  = (const float*)d_in[1];
    const float* V  = (const float*)d_in[2];
    const int*   mf = (const int*)d_in[3];
    float* O = (float*)d_out;

    char* wsb = (char*)d_ws;
    u64*    keys     = (u64*)wsb;                                   // 128 KB
    u32*    cnt      = (u32*)(wsb + 131072);
    u32*    list     = (u32*)(wsb + 131072 + 256);                  // 64 KB
    float2* meta     = (float2*)(wsb + 131072 + 256 + 65536);       // 4 KB
    float*  partials = (float*)(wsb + 131072 + 256 + 65536 + 8192); // 1 MB

    const size_t SPLIT_OFF = 1310720;                 // 1.25 MB, 16B-aligned
    const size_t ARR = (size_t)BATCH * SEQ * 256 * 4; // 16 MB per array
    u32* Qh = (u32*)(wsb + SPLIT_OFF);
    u32* Ql = (u32*)(wsb + SPLIT_OFF + ARR);
    u32* Kh = (u32*)(wsb + SPLIT_OFF + 2 * ARR);
    u32* Kl = (u32*)(wsb + SPLIT_OFF + 3 * ARR);
    const bool big_ws = ws_size >= SPLIT_OFF + 4 * ARR;

    hipMemsetAsync(keys, 0xFF, (size_t)BATCH * SEQ * sizeof(u64), stream);
    hipMemsetAsync(cnt, 0, sizeof(u32), stream);

    if (big_ws) {
        prep_kernel<<<dim3(3072), dim3(256), 0, stream>>>(Q, K, Qh, Ql, Kh, Kl);
        argmin5_kernel<<<dim3(1088), dim3(256), 0, stream>>>(Qh, Ql, Kh, Kl, mf, keys);
    } else {
        argmin_lds_kernel<<<dim3(BATCH * 272), dim3(512), 0, stream>>>(Q, K, mf, keys);
    }
    gather_kernel<<<dim3(BATCH * (SEQ / 64)), dim3(512), 0, stream>>>(V, keys, cnt, list, O);
    fb_part_kernel<<<dim3(512), dim3(512), 0, stream>>>(Q, K, V, mf, cnt, list, meta, partials);
    fb_combine_kernel<<<dim3(128), dim3(512), 0, stream>>>(Q, K, V, mf, cnt, list, meta, partials, O);
}